// Round 4
// baseline (6927.708 us; speedup 1.0000x reference)
//
#include <hip/hip_runtime.h>
#include <hip/hip_fp16.h>

typedef float f32x4 __attribute__((ext_vector_type(4)));
typedef _Float16 f16x8 __attribute__((ext_vector_type(8)));
typedef _Float16 f16x4 __attribute__((ext_vector_type(4)));

// ---------------- LDS byte map (regions alias across phases) ----------------
// LDSB = 40368 -> LDS allows 4 blocks/CU (3 needed: 3*40368 = 121KB <= 160KB).
// Register model (measured r0-r3): launch_bounds(256,N) makes the compiler
// split the unified 512-reg file EVENLY: accum_offset = budget/2, and HW
// allocates the FULL budget (arch+agpr halves). Observed arch counts
// 128/84/64 for N=2/3/4 — always budget/2, occupancy always budget-bound.
//   r2: (256,3) + acc[4][4]=64 AGPR -> only 20 free AGPRs, 44-reg overflow
//       went to SCRATCH (FETCH 3.4e6 KB) -> 6806 us.
//   r3: pixel-split acc[4][2]=32 AGPR + (256,2): clean (FETCH 4.6e5) but
//       full 256-reg allocation -> still 2 waves/SIMD -> 5951 us.
// THIS ROUND: pixel-split + (256,3): arch cap 84, acc 32 AGPR -> 52 free
// AGPR slots absorb the ~44-reg arch overflow via v_accvgpr spills (on-chip,
// no scratch) -> 3 waves/SIMD, 3 blocks/CU.
// Lifetimes:
//   region A (0..12936):      XF (conv0 out, phase A)  ->  PL (planes, phase B)
//   region B (12944..38816):  XP (x staged f16 [49][528])        [dies after conv0]
//                             XF2 (conv1 out [49][264]) @12944   [dies after static conv reads]
//                             ST  (static gates f16 [49][528]) persists phase B
//   FCP @38816 (1 KiB fc partials), PRD @39840 (2 ints), Z512 @39856 (zeros, OOB fallback)
#define XP    12944
#define XF    0
#define XF2   12944
#define PL    0
#define ST    12944
#define STSTR 528
#define FCP   38816
#define PRD   39840
#define Z512  39856
#define LDSB  40368

__device__ __forceinline__ float sigmoidf_(float v) { return 1.0f / (1.0f + expf(-v)); }

// exact floor(p/7) for p in [0,48]
__device__ __forceinline__ int div7_(int p) { return (p * 37) >> 8; }

// shifted-window conv GEMM, weights hi/lo f16 (A), acts single f16 (B):
// acc += Al*B + Ah*B. Geometry recomputed per call from (nBase,l15) — no
// persistent geometry registers. Tap loop deliberately NOT unrolled: keeps
// the scheduling window small so the allocator doesn't hoist 9 taps' worth
// of loads and spill acc to scratch.
template <int NKC, int NMI, int NN>
__device__ __forceinline__ void conv_mfma_run(
    const char* __restrict__ SHb, int baseB, int pstr2,
    const int (&kofs)[NKC], int q16,
    const _Float16* __restrict__ ghi, const _Float16* __restrict__ glo,
    int NMF, int miBase, int miStep,
    int nBase, int l15,
    f32x4 (&acc)[NMI][NN], int lane)
{
    int okc[NN], py0[NN], px0[NN];
    #pragma unroll
    for (int nn = 0; nn < NN; ++nn) {
        int col = (nBase + nn) * 16 + l15;
        okc[nn] = col < 49;
        int p = okc[nn] ? col : 0;
        py0[nn] = div7_(p); px0[nn] = p - py0[nn] * 7;
    }
    #pragma unroll 1
    for (int tap = 0; tap < 9; ++tap) {
        const int dy = tap / 3 - 1, dx = tap % 3 - 1;
        int bb[NN];
        #pragma unroll
        for (int nn = 0; nn < NN; ++nn) {
            int py = py0[nn] + dy, px = px0[nn] + dx;
            bool ok = okc[nn] && ((unsigned)py < 7u) && ((unsigned)px < 7u);
            bb[nn] = ok ? baseB + (py * 7 + px) * pstr2 : Z512;  // Z512+kof<=Z512+496: zeros
        }
        #pragma unroll
        for (int kc = 0; kc < NKC; ++kc) {
            const int kof = kofs[kc] + q16;
            f16x8 B[NN];
            #pragma unroll
            for (int nn = 0; nn < NN; ++nn) B[nn] = *(const f16x8*)(SHb + bb[nn] + kof);
            #pragma unroll
            for (int ii = 0; ii < NMI; ++ii) {
                int frag = (((tap * NKC + kc) * NMF + (miBase + ii * miStep)) << 9) + lane * 8;
                f16x8 Ah = *(const f16x8*)(ghi + frag);
                f16x8 Al = *(const f16x8*)(glo + frag);
                #pragma unroll
                for (int nn = 0; nn < NN; ++nn) {
                    acc[ii][nn] = __builtin_amdgcn_mfma_f32_16x16x32_f16(Al, B[nn], acc[ii][nn], 0, 0, 0);
                    acc[ii][nn] = __builtin_amdgcn_mfma_f32_16x16x32_f16(Ah, B[nn], acc[ii][nn], 0, 0, 0);
                }
            }
        }
    }
}

// one-hot map conv contribution injected at acc-init (map one-hot at pixel pv)
template <int NN>
__device__ __forceinline__ void inject_onehot(
    f32x4 (&acc)[4][NN], const float* __restrict__ wv, int pv,
    int nBase, int l15, int w, int q)
{
    if (pv >= 49) return;                 // EOS / empty map
    int vy = div7_(pv), vx = pv - vy * 7;
    #pragma unroll
    for (int nn = 0; nn < NN; ++nn) {
        int col = (nBase + nn) * 16 + l15;
        int ok = col < 49;
        int p = ok ? col : 0;
        int py = div7_(p), px = p - py * 7;
        int dy = vy - py, dx = vx - px;
        if (ok && dy >= -1 && dy <= 1 && dx >= -1 && dx <= 1) {
            int tap = (dy + 1) * 3 + (dx + 1);
            const float* wp = wv + tap * 256 + w * 16 + q * 4;
            #pragma unroll
            for (int g = 0; g < 4; ++g)
                acc[g][nn] += *(const f32x4*)(wp + g * 64);
        }
    }
}

extern "C" __global__ __launch_bounds__(256, 3)
void poly_fused(const float* __restrict__ x, const int* __restrict__ firstv,
                const float* __restrict__ b_c0, const float* __restrict__ b_c1,
                const float* __restrict__ cx0b, const float* __restrict__ ch0b,
                const float* __restrict__ cx1b, const float* __restrict__ ch1b,
                const float* __restrict__ fcb,
                const _Float16* __restrict__ c0hi, const _Float16* __restrict__ c0lo,
                const _Float16* __restrict__ c1hi, const _Float16* __restrict__ c1lo,
                const _Float16* __restrict__ cshi, const _Float16* __restrict__ cslo,
                const _Float16* __restrict__ g0hi, const _Float16* __restrict__ g0lo,
                const _Float16* __restrict__ g1hi, const _Float16* __restrict__ g1lo,
                const _Float16* __restrict__ fchi, const _Float16* __restrict__ fclo,
                const float* __restrict__ wv1,
                const float* __restrict__ wvp1, const float* __restrict__ wvp2,
                float* __restrict__ out)
{
    extern __shared__ char SHC[];
    float* SHf = (float*)SHC;
    const int tid = threadIdx.x, s = blockIdx.x;
    const int lane = tid & 63, w = tid >> 6;
    const int q = lane >> 4, l15 = lane & 15, q16 = q * 16;

    for (int i = tid; i < LDSB / 4; i += 256) SHf[i] = 0.f;
    __syncthreads();

    // ============ PHASE A ============
    const float* xs = x + (size_t)s * 12544;
    for (int e = tid; e < 12544; e += 256) {
        int ch = e / 49, p = e - ch * 49;
        *(_Float16*)(SHC + XP + p * 528 + ch * 2) = (_Float16)xs[e];
    }
    __syncthreads();                       // XP visible

    const int kofs8[8] = {0, 64, 128, 192, 256, 320, 384, 448};
    const int kofs4[4] = {0, 64, 128, 192};
    const int kofs2[2] = {0, 64};

    // conv0: M=128 (8 mfrags; wave owns w*2, w*2+1), K=256; XP -> XF
    {
        f32x4 acc2[2][4];
        #pragma unroll
        for (int ii = 0; ii < 2; ++ii)
            #pragma unroll
            for (int n = 0; n < 4; ++n) acc2[ii][n] = (f32x4){0.f, 0.f, 0.f, 0.f};
        conv_mfma_run<8, 2, 4>(SHC, XP, 528, kofs8, q16, c0hi, c0lo,
                               8, w * 2, 1, 0, l15, acc2, lane);
        #pragma unroll
        for (int ii = 0; ii < 2; ++ii) {
            f32x4 bb = *(const f32x4*)(b_c0 + (w * 2 + ii) * 16 + q * 4);
            int chB = ((w * 2 + ii) * 16 + q * 4) * 2;
            #pragma unroll
            for (int n = 0; n < 4; ++n) {
                int col = n * 16 + l15;
                if (col < 49) {
                    f16x4 h;
                    #pragma unroll
                    for (int r = 0; r < 4; ++r)
                        h[r] = (_Float16)fmaxf(acc2[ii][n][r] + bb[r], 0.f);
                    *(f16x4*)(SHC + XF + col * 264 + chB) = h;
                }
            }
        }
    }
    __syncthreads();                       // XF visible; XP dead

    // conv1: M=128, K=128, XF -> XF2 (XF2 lives in XP's old bytes)
    {
        f32x4 acc2[2][4];
        #pragma unroll
        for (int ii = 0; ii < 2; ++ii)
            #pragma unroll
            for (int n = 0; n < 4; ++n) acc2[ii][n] = (f32x4){0.f, 0.f, 0.f, 0.f};
        conv_mfma_run<4, 2, 4>(SHC, XF, 264, kofs4, q16, c1hi, c1lo,
                               8, w * 2, 1, 0, l15, acc2, lane);
        #pragma unroll
        for (int ii = 0; ii < 2; ++ii) {
            f32x4 bb = *(const f32x4*)(b_c1 + (w * 2 + ii) * 16 + q * 4);
            int chB = ((w * 2 + ii) * 16 + q * 4) * 2;
            #pragma unroll
            for (int n = 0; n < 4; ++n) {
                int col = n * 16 + l15;
                if (col < 49) {
                    f16x4 h;
                    #pragma unroll
                    for (int r = 0; r < 4; ++r)
                        h[r] = (_Float16)fmaxf(acc2[ii][n][r] + bb[r], 0.f);
                    *(f16x4*)(SHC + XF2 + col * 264 + chB) = h;
                }
            }
        }
    }
    __syncthreads();                       // XF2 visible; XF dead

    // static gates: st = conv_cs(x_feat) + (cx0b+ch0b) + v_first window.
    // Pixel-split into two conv runs (acc[4][2] = 32 regs each); half 0 is
    // packed to f16 in regs while half 1 runs; stores only after the barrier
    // (ST aliases XF2 — all reads must complete first).
    const int fv = firstv[s];
    const int fy = div7_(fv), fx = fv - fy * 7;
    {
        auto finalize = [&](f32x4 (&a)[4][2], int nBase) {
            #pragma unroll
            for (int g = 0; g < 4; ++g) {
                int m0 = g * 64 + w * 16 + q * 4;
                f32x4 b0 = *(const f32x4*)(cx0b + m0);
                f32x4 bh = *(const f32x4*)(ch0b + m0);
                #pragma unroll
                for (int nn = 0; nn < 2; ++nn) {
                    a[g][nn] += b0 + bh;
                    int col = (nBase + nn) * 16 + l15;
                    int ok = col < 49;
                    int p = ok ? col : 0;
                    int py = div7_(p), px = p - py * 7;
                    int dy = fy - py, dx = fx - px;
                    if (ok && dy >= -1 && dy <= 1 && dx >= -1 && dx <= 1) {
                        int tap = (dy + 1) * 3 + (dx + 1);
                        a[g][nn] += *(const f32x4*)(wv1 + tap * 256 + m0);
                    }
                }
            }
        };
        f16x4 stP[4][2];                   // half-0 result, packed f16
        {
            f32x4 acc[4][2];
            #pragma unroll
            for (int g = 0; g < 4; ++g)
                #pragma unroll
                for (int nn = 0; nn < 2; ++nn) acc[g][nn] = (f32x4){0.f, 0.f, 0.f, 0.f};
            conv_mfma_run<4, 4, 2>(SHC, XF2, 264, kofs4, q16, cshi, cslo,
                                   16, w, 4, 0, l15, acc, lane);
            finalize(acc, 0);
            #pragma unroll
            for (int g = 0; g < 4; ++g)
                #pragma unroll
                for (int nn = 0; nn < 2; ++nn)
                    #pragma unroll
                    for (int r = 0; r < 4; ++r) stP[g][nn][r] = (_Float16)acc[g][nn][r];
        }
        f32x4 accH[4][2];
        #pragma unroll
        for (int g = 0; g < 4; ++g)
            #pragma unroll
            for (int nn = 0; nn < 2; ++nn) accH[g][nn] = (f32x4){0.f, 0.f, 0.f, 0.f};
        conv_mfma_run<4, 4, 2>(SHC, XF2, 264, kofs4, q16, cshi, cslo,
                               16, w, 4, 2, l15, accH, lane);
        finalize(accH, 2);
        __syncthreads();                   // ALL waves' XF2 reads done; safe to write ST
        #pragma unroll
        for (int g = 0; g < 4; ++g) {
            int m0 = g * 64 + w * 16 + q * 4;
            #pragma unroll
            for (int nn = 0; nn < 2; ++nn) {
                int colA = nn * 16 + l15;
                if (colA < 49)
                    *(f16x4*)(SHC + ST + colA * STSTR + m0 * 2) = stP[g][nn];
                int colB = (2 + nn) * 16 + l15;
                if (colB < 49) {
                    f16x4 hB;
                    #pragma unroll
                    for (int r = 0; r < 4; ++r) hB[r] = (_Float16)accH[g][nn][r];
                    *(f16x4*)(SHC + ST + colB * STSTR + m0 * 2) = hB;
                }
            }
        }
    }
    // zero PL (aliases XF, dead) + init preds: vp1 = v_first, vp2 = empty(49)
    for (int i = tid; i < 12936 / 4; i += 256) SHf[i] = 0.f;
    if (tid == 0) { ((int*)(SHC + PRD))[0] = fv; ((int*)(SHC + PRD))[1] = 49; }
    __syncthreads();                       // ST, PL, PRD visible

    float c0s[4][4], c1s[4][4];
    #pragma unroll
    for (int n = 0; n < 4; ++n)
        #pragma unroll
        for (int r = 0; r < 4; ++r) { c0s[n][r] = 0.f; c1s[n][r] = 0.f; }

    float* outS = out + (size_t)s * 450;

    // ============ PHASE B: 9 recurrent steps ============
    for (int t = 0; t < 9; ++t) {
        int p1 = ((const int*)(SHC + PRD))[0];
        int p2 = ((const int*)(SHC + PRD))[1];
        // ---- L0: pixel-split; both halves only READ h0-old/ST/PRD ----
        f16x4 h0p[2][2];
        #pragma unroll
        for (int hh = 0; hh < 2; ++hh) {
            f32x4 acc[4][2];
            #pragma unroll
            for (int g = 0; g < 4; ++g) {
                int m0 = g * 64 + w * 16 + q * 4;
                #pragma unroll
                for (int nn = 0; nn < 2; ++nn) {
                    int col = (2 * hh + nn) * 16 + l15;
                    int p = col < 49 ? col : 0;
                    f16x4 hv = *(const f16x4*)(SHC + ST + p * STSTR + m0 * 2);
                    acc[g][nn] = (f32x4){(float)hv[0], (float)hv[1], (float)hv[2], (float)hv[3]};
                }
            }
            inject_onehot<2>(acc, wvp1, p1, 2 * hh, l15, w, q);
            inject_onehot<2>(acc, wvp2, p2, 2 * hh, l15, w, q);
            conv_mfma_run<2, 4, 2>(SHC, PL, 264, kofs2, q16, g0hi, g0lo,
                                   16, w, 4, 2 * hh, l15, acc, lane);
            #pragma unroll
            for (int nn = 0; nn < 2; ++nn) {
                int n = 2 * hh + nn;
                #pragma unroll
                for (int r = 0; r < 4; ++r) {
                    float ig = sigmoidf_(acc[0][nn][r]);
                    float fg = sigmoidf_(acc[1][nn][r]);
                    float gg = tanhf(acc[2][nn][r]);
                    float og = sigmoidf_(acc[3][nn][r]);
                    float cy = fg * c0s[n][r] + ig * gg;
                    c0s[n][r] = cy;
                    h0p[hh][nn][r] = (_Float16)(og * tanhf(cy));
                }
            }
        }
        __syncthreads();                   // L0 reads of h0-old done
        {
            int chB = (w * 16 + q * 4) * 2;
            #pragma unroll
            for (int hh = 0; hh < 2; ++hh)
                #pragma unroll
                for (int nn = 0; nn < 2; ++nn) {
                    int col = (2 * hh + nn) * 16 + l15;
                    if (col < 49) *(f16x4*)(SHC + PL + col * 264 + chB) = h0p[hh][nn];
                }
        }
        __syncthreads();                   // h0 visible
        // ---- L1: K = [h0 new | h1 old] = PL ch 0..127; pixel-split ----
        f16x4 h1p[2][2];
        #pragma unroll
        for (int hh = 0; hh < 2; ++hh) {
            f32x4 acc[4][2];
            #pragma unroll
            for (int g = 0; g < 4; ++g) {
                int m0 = g * 64 + w * 16 + q * 4;
                f32x4 bb = *(const f32x4*)(cx1b + m0) + *(const f32x4*)(ch1b + m0);
                acc[g][0] = bb; acc[g][1] = bb;
            }
            conv_mfma_run<4, 4, 2>(SHC, PL, 264, kofs4, q16, g1hi, g1lo,
                                   16, w, 4, 2 * hh, l15, acc, lane);
            #pragma unroll
            for (int nn = 0; nn < 2; ++nn) {
                int n = 2 * hh + nn;
                #pragma unroll
                for (int r = 0; r < 4; ++r) {
                    float ig = sigmoidf_(acc[0][nn][r]);
                    float fg = sigmoidf_(acc[1][nn][r]);
                    float gg = tanhf(acc[2][nn][r]);
                    float og = sigmoidf_(acc[3][nn][r]);
                    float cy = fg * c1s[n][r] + ig * gg;
                    c1s[n][r] = cy;
                    h1p[hh][nn][r] = (_Float16)(og * tanhf(cy));
                }
            }
        }
        __syncthreads();                   // L1 reads of h1-old done
        {
            int chB = 128 + (w * 16 + q * 4) * 2;
            #pragma unroll
            for (int hh = 0; hh < 2; ++hh)
                #pragma unroll
                for (int nn = 0; nn < 2; ++nn) {
                    int col = (2 * hh + nn) * 16 + l15;
                    if (col < 49) *(f16x4*)(SHC + PL + col * 264 + chB) = h1p[hh][nn];
                }
        }
        __syncthreads();                   // h1 visible (fc input)
        {   // fc via MFMA: M=64 (50 live), K=3136 from PL h1; col 0 live
            f32x4 afc[4];
            #pragma unroll
            for (int mi = 0; mi < 4; ++mi) afc[mi] = (f32x4){0.f, 0.f, 0.f, 0.f};
            int kc0 = w * 25;
            int kcN = (w < 3) ? 25 : 23;
            #pragma unroll 1
            for (int kc = 0; kc < kcN; ++kc) {
                int kg = kc0 + kc;
                int aB = (l15 == 0) ? (PL + (kg >> 1) * 264 + 128 + (kg & 1) * 64 + q16) : Z512;
                f16x8 B = *(const f16x8*)(SHC + aB);
                #pragma unroll
                for (int mi = 0; mi < 4; ++mi) {
                    int frag = ((kg * 4 + mi) << 9) + lane * 8;
                    f16x8 Ah = *(const f16x8*)(fchi + frag);
                    f16x8 Al = *(const f16x8*)(fclo + frag);
                    afc[mi] = __builtin_amdgcn_mfma_f32_16x16x32_f16(Al, B, afc[mi], 0, 0, 0);
                    afc[mi] = __builtin_amdgcn_mfma_f32_16x16x32_f16(Ah, B, afc[mi], 0, 0, 0);
                }
            }
            if (l15 == 0) {
                #pragma unroll
                for (int mi = 0; mi < 4; ++mi)
                    *(f32x4*)(SHC + FCP + w * 256 + mi * 64 + q16) = afc[mi];
            }
        }
        __syncthreads();                   // fc partials visible
        if (tid < 64) {
            int c = tid;
            const float* fp = (const float*)(SHC + FCP);
            float lg = fp[c] + fp[64 + c] + fp[128 + c] + fp[192 + c];
            float v = -3.4e38f;
            if (c < 50) { lg += fcb[c]; outS[t * 50 + c] = lg; v = lg; }
            int idx = c;
            #pragma unroll
            for (int off = 1; off < 64; off <<= 1) {
                float ov = __shfl_xor(v, off, 64);
                int   oi = __shfl_xor(idx, off, 64);
                if (ov > v || (ov == v && oi < idx)) { v = ov; idx = oi; }
            }
            if (c == 0) {
                int* pr = (int*)(SHC + PRD);
                pr[1] = pr[0];             // vp2 <- vp1
                pr[0] = idx;               // vp1 <- one-hot(pred)
            }
        }
        __syncthreads();                   // PRD visible; FCP reusable
    }
}

// ================= weight repack kernels =================
// OIHW conv weights -> A fragments [tap][kc][mi][lane][8], hi/lo f16 split
__global__ void repack_frags_k(const float* __restrict__ w, _Float16* __restrict__ ohi,
                               _Float16* __restrict__ olo, int ICS, int KMAX,
                               int NKC, int NMF, int total) {
    int i = blockIdx.x * 256 + threadIdx.x;
    if (i >= total) return;
    int j = i & 7, lane = (i >> 3) & 63;
    int rest = i >> 9;
    int mi = rest % NMF; rest /= NMF;
    int kc = rest % NKC; int tap = rest / NKC;
    int m = mi * 16 + (lane & 15);
    int k = kc * 32 + ((lane >> 4) & 3) * 8 + j;
    float v = (k < KMAX) ? w[((size_t)m * ICS + k) * 9 + tap] : 0.f;
    _Float16 hv = (_Float16)v;
    ohi[i] = hv; olo[i] = (_Float16)(v - (float)hv);
}

__global__ void repack_g1_k(const float* __restrict__ cx1w, const float* __restrict__ ch1w,
                            _Float16* __restrict__ ohi, _Float16* __restrict__ olo) {
    int i = blockIdx.x * 256 + threadIdx.x;
    if (i >= 294912) return;
    int j = i & 7; int lane = (i >> 3) & 63; int mt = (i >> 9) & 15;
    int rest = i >> 13; int kc = rest & 3; int tap = rest >> 2;
    int m = mt * 16 + (lane & 15);
    int kk = (lane >> 4) * 8 + j;
    float wv;
    if (kc < 2) wv = cx1w[((size_t)m * 64 + kc * 32 + kk) * 9 + tap];
    else        wv = ch1w[((size_t)m * 64 + (kc - 2) * 32 + kk) * 9 + tap];
    _Float16 hv = (_Float16)wv;
    ohi[i] = hv; olo[i] = (_Float16)(wv - (float)hv);
}

// fc weights [50][3136] -> frags [kc 98][mi 4][lane][8], k = p*64+ch
__global__ void repack_fc_k(const float* __restrict__ fcw, _Float16* __restrict__ ohi,
                            _Float16* __restrict__ olo) {
    int i = blockIdx.x * 256 + threadIdx.x;
    if (i >= 200704) return;
    int j = i & 7, lane = (i >> 3) & 63;
    int rest = i >> 9;
    int mi = rest & 3, kc = rest >> 2;
    int cls = mi * 16 + (lane & 15);
    int k = kc * 32 + ((lane >> 4) & 3) * 8 + j;
    int ch = k & 63, p = k >> 6;
    float v = (cls < 50) ? fcw[(size_t)cls * 3136 + ch * 49 + p] : 0.f;
    _Float16 hv = (_Float16)v;
    ohi[i] = hv; olo[i] = (_Float16)(v - (float)hv);
}

// one-hot conv tables: wv[tap][m] = cx0w[m, ic, tap]
__global__ void repack_wv_k(const float* __restrict__ cx0w, float* __restrict__ o, int ic) {
    int i = blockIdx.x * 256 + threadIdx.x;
    if (i >= 2304) return;
    int tap = i / 256, m = i % 256;
    o[i] = cx0w[((size_t)m * 131 + ic) * 9 + tap];
}

extern "C" void kernel_launch(void* const* d_in, const int* in_sizes, int n_in,
                              void* d_out, int out_size, void* d_ws, size_t ws_size,
                              hipStream_t stream)
{
    const float* x     = (const float*)d_in[0];
    const int*   fv    = (const int*)  d_in[1];
    const float* c0w   = (const float*)d_in[2];
    const float* c0b   = (const float*)d_in[3];
    const float* c1w   = (const float*)d_in[4];
    const float* c1b   = (const float*)d_in[5];
    const float* cx0w  = (const float*)d_in[6];
    const float* cx0b  = (const float*)d_in[7];
    const float* ch0w  = (const float*)d_in[8];
    const float* ch0b  = (const float*)d_in[9];
    const float* cx1w  = (const float*)d_in[10];
    const float* cx1b  = (const float*)d_in[11];
    const float* ch1w  = (const float*)d_in[12];
    const float* ch1b  = (const float*)d_in[13];
    const float* fcw   = (const float*)d_in[14];
    const float* fcb   = (const float*)d_in[15];
    float* out = (float*)d_out;
    const int n = in_sizes[0] / 12544;

    _Float16* h = (_Float16*)d_ws;
    _Float16* g0hi = h;                  // 147456 (NKC=2, NMF=16)
    _Float16* g0lo = g0hi + 147456;
    _Float16* g1hi = g0lo + 147456;      // 294912
    _Float16* g1lo = g1hi + 294912;
    _Float16* c0hi = g1lo + 294912;      // 294912
    _Float16* c0lo = c0hi + 294912;
    _Float16* c1hi = c0lo + 294912;      // 147456
    _Float16* c1lo = c1hi + 147456;
    _Float16* cshi = c1lo + 147456;      // 294912
    _Float16* cslo = cshi + 294912;
    _Float16* fchi = cslo + 294912;      // 200704
    _Float16* fclo = fchi + 200704;
    float*    wv1  = (float*)(fclo + 200704);   // 2304 f32 each
    float*    wvp1 = wv1 + 2304;
    float*    wvp2 = wvp1 + 2304;

    repack_frags_k<<<(147456 + 255) / 256, 256, 0, stream>>>(ch0w, g0hi, g0lo, 64, 64, 2, 16, 147456);
    repack_g1_k   <<<(294912 + 255) / 256, 256, 0, stream>>>(cx1w, ch1w, g1hi, g1lo);
    repack_frags_k<<<(294912 + 255) / 256, 256, 0, stream>>>(c0w, c0hi, c0lo, 256, 256, 8, 8, 294912);
    repack_frags_k<<<(147456 + 255) / 256, 256, 0, stream>>>(c1w, c1hi, c1lo, 128, 128, 4, 8, 147456);
    repack_frags_k<<<(294912 + 255) / 256, 256, 0, stream>>>(cx0w, cshi, cslo, 131, 128, 4, 16, 294912);
    repack_fc_k   <<<(200704 + 255) / 256, 256, 0, stream>>>(fcw, fchi, fclo);
    repack_wv_k   <<<(2304 + 255) / 256, 256, 0, stream>>>(cx0w, wv1, 130);
    repack_wv_k   <<<(2304 + 255) / 256, 256, 0, stream>>>(cx0w, wvp1, 129);
    repack_wv_k   <<<(2304 + 255) / 256, 256, 0, stream>>>(cx0w, wvp2, 128);

    (void)hipFuncSetAttribute((const void*)poly_fused,
                              hipFuncAttributeMaxDynamicSharedMemorySize, LDSB);
    poly_fused<<<n, 256, LDSB, stream>>>(x, fv, c0b, c1b, cx0b, ch0b, cx1b, ch1b, fcb,
                                         c0hi, c0lo, c1hi, c1lo, cshi, cslo,
                                         g0hi, g0lo, g1hi, g1lo, fchi, fclo,
                                         wv1, wvp1, wvp2, out);
}

// Round 5
// 2826.348 us; speedup vs baseline: 2.4511x; 2.4511x over previous
//
#include <hip/hip_runtime.h>
#include <hip/hip_fp16.h>

typedef float f32x4 __attribute__((ext_vector_type(4)));
typedef _Float16 f16x8 __attribute__((ext_vector_type(8)));
typedef _Float16 f16x4 __attribute__((ext_vector_type(4)));

// ---------------- LDS byte map (regions alias across phases) ----------------
// Register model (measured r0-r4): launch_bounds(256,N) splits the unified
// 512-reg file EVENLY (arch = budget/2: observed 128/84/64 for N=2/3/4) and
// HW allocates the FULL budget. Kernel naturally needs ~128 arch regs, so:
//   (256,2): clean, 2 waves/SIMD, 24% occ  (r0: 4986 us)
//   (256,3): 84-reg arch cap -> ~1.5 GB scratch spill (r2: 6806, r4: 6928)
//   (256,4): 64-reg cap -> 13 GB spill (r1: 7432)
// Occupancy is capped at 2 waves/SIMD for this structure. This round instead
// cuts the per-wave critical path: r3-vs-r0 delta showed ~70 cyc exposed
// stall per global A-frag load (latency-bound on L2-resident weight frags).
// g0/g1 lo-correction MFMAs contribute ~2^-11 relative — same order as the
// f16 activation rounding, and squashed by sigmoid/tanh — so phase-B gate
// convs run single-f16 (HILO=false): halves their MFMAs AND A-frag loads.
// Lifetimes:
//   region A (0..12936):      XF (conv0 out, phase A)  ->  PL (planes, phase B)
//   region B (12944..38816):  XP (x staged f16 [49][528])        [dies after conv0]
//                             XF2 (conv1 out [49][264]) @12944   [dies after static conv reads]
//                             ST  (static gates f16 [49][528]) persists phase B
//   FCP @38816 (1 KiB fc partials), PRD @39840 (2 ints), Z512 @39856 (zeros, OOB fallback)
// ST aliases XF2: phase A finalizes static gates in registers, barriers,
// THEN stores (all XF2 reads complete before any ST write).
#define XP    12944
#define XF    0
#define XF2   12944
#define PL    0
#define ST    12944
#define STSTR 528
#define FCP   38816
#define PRD   39840
#define Z512  39856
#define LDSB  40368

__device__ __forceinline__ float sigmoidf_(float v) { return 1.0f / (1.0f + expf(-v)); }

// shifted-window conv GEMM, weights f16 (A), acts single f16 (B):
// HILO=true: acc += Al*B + Ah*B (hi/lo split-f16 ~f32-accurate weights).
// HILO=false: acc += Ah*B (single f16 weights; halves MFMAs and A-loads).
// Tap loop deliberately NOT unrolled: keeps the scheduling window small so
// the allocator doesn't hoist 9 taps' worth of loads and spill acc.
template <int NKC, int NMI, bool HILO = true>
__device__ __forceinline__ void conv_mfma_run(
    const char* __restrict__ SHb, int baseB, int pstr2,
    const int (&kofs)[NKC], int q16,
    const _Float16* __restrict__ ghi, const _Float16* __restrict__ glo,
    int NMF, int miBase, int miStep,
    const int (&okc)[4], const int (&py0)[4], const int (&px0)[4],
    f32x4 (&acc)[NMI][4], int lane)
{
    #pragma unroll 1
    for (int tap = 0; tap < 9; ++tap) {
        const int dy = tap / 3 - 1, dx = tap % 3 - 1;
        int bb[4];
        #pragma unroll
        for (int n = 0; n < 4; ++n) {
            int py = py0[n] + dy, px = px0[n] + dx;
            bool ok = okc[n] && ((unsigned)py < 7u) && ((unsigned)px < 7u);
            bb[n] = ok ? baseB + (py * 7 + px) * pstr2 : Z512;  // Z512+kof<=Z512+496: zeros
        }
        #pragma unroll
        for (int kc = 0; kc < NKC; ++kc) {
            const int kof = kofs[kc] + q16;
            f16x8 B[4];
            #pragma unroll
            for (int n = 0; n < 4; ++n) B[n] = *(const f16x8*)(SHb + bb[n] + kof);
            #pragma unroll
            for (int ii = 0; ii < NMI; ++ii) {
                int frag = (((tap * NKC + kc) * NMF + (miBase + ii * miStep)) << 9) + lane * 8;
                f16x8 Ah = *(const f16x8*)(ghi + frag);
                if constexpr (HILO) {
                    f16x8 Al = *(const f16x8*)(glo + frag);
                    #pragma unroll
                    for (int n = 0; n < 4; ++n) {
                        acc[ii][n] = __builtin_amdgcn_mfma_f32_16x16x32_f16(Al, B[n], acc[ii][n], 0, 0, 0);
                        acc[ii][n] = __builtin_amdgcn_mfma_f32_16x16x32_f16(Ah, B[n], acc[ii][n], 0, 0, 0);
                    }
                } else {
                    #pragma unroll
                    for (int n = 0; n < 4; ++n)
                        acc[ii][n] = __builtin_amdgcn_mfma_f32_16x16x32_f16(Ah, B[n], acc[ii][n], 0, 0, 0);
                }
            }
        }
    }
}

// one-hot map conv contribution injected at acc-init (map one-hot at pixel pv)
__device__ __forceinline__ void inject_onehot(
    f32x4 (&acc)[4][4], const float* __restrict__ wv, int pv,
    const int (&okc)[4], const int (&py0)[4], const int (&px0)[4], int w, int q)
{
    if (pv >= 49) return;                 // EOS / empty map
    int vy = pv / 7, vx = pv % 7;
    #pragma unroll
    for (int n = 0; n < 4; ++n) {
        int dy = vy - py0[n], dx = vx - px0[n];
        if (okc[n] && dy >= -1 && dy <= 1 && dx >= -1 && dx <= 1) {
            int tap = (dy + 1) * 3 + (dx + 1);
            const float* wp = wv + tap * 256 + w * 16 + q * 4;
            #pragma unroll
            for (int g = 0; g < 4; ++g)
                acc[g][n] += *(const f32x4*)(wp + g * 64);
        }
    }
}

extern "C" __global__ __launch_bounds__(256, 2)
void poly_fused(const float* __restrict__ x, const int* __restrict__ firstv,
                const float* __restrict__ b_c0, const float* __restrict__ b_c1,
                const float* __restrict__ cx0b, const float* __restrict__ ch0b,
                const float* __restrict__ cx1b, const float* __restrict__ ch1b,
                const float* __restrict__ fcb,
                const _Float16* __restrict__ c0hi, const _Float16* __restrict__ c0lo,
                const _Float16* __restrict__ c1hi, const _Float16* __restrict__ c1lo,
                const _Float16* __restrict__ cshi, const _Float16* __restrict__ cslo,
                const _Float16* __restrict__ g0hi, const _Float16* __restrict__ g0lo,
                const _Float16* __restrict__ g1hi, const _Float16* __restrict__ g1lo,
                const _Float16* __restrict__ fchi, const _Float16* __restrict__ fclo,
                const float* __restrict__ wv1,
                const float* __restrict__ wvp1, const float* __restrict__ wvp2,
                float* __restrict__ out)
{
    extern __shared__ char SHC[];
    float* SHf = (float*)SHC;
    const int tid = threadIdx.x, s = blockIdx.x;
    const int lane = tid & 63, w = tid >> 6;
    const int q = lane >> 4, l15 = lane & 15, q16 = q * 16;

    for (int i = tid; i < LDSB / 4; i += 256) SHf[i] = 0.f;
    __syncthreads();

    // per-lane column geometry (col = n*16 + l15; 49 live pixels)
    int okc[4], py0[4], px0[4];
    #pragma unroll
    for (int n = 0; n < 4; ++n) {
        int col = n * 16 + l15;
        okc[n] = col < 49;
        int p = okc[n] ? col : 0;
        py0[n] = p / 7; px0[n] = p % 7;
    }

    // ============ PHASE A ============
    const float* xs = x + (size_t)s * 12544;
    for (int e = tid; e < 12544; e += 256) {
        int ch = e / 49, p = e - ch * 49;
        *(_Float16*)(SHC + XP + p * 528 + ch * 2) = (_Float16)xs[e];
    }
    __syncthreads();                       // XP visible

    const int kofs8[8] = {0, 64, 128, 192, 256, 320, 384, 448};
    const int kofs4[4] = {0, 64, 128, 192};
    const int kofs2[2] = {0, 64};

    // conv0: M=128 (8 mfrags; wave owns w*2, w*2+1), K=256; XP -> XF
    {
        f32x4 acc2[2][4];
        #pragma unroll
        for (int ii = 0; ii < 2; ++ii)
            #pragma unroll
            for (int n = 0; n < 4; ++n) acc2[ii][n] = (f32x4){0.f, 0.f, 0.f, 0.f};
        conv_mfma_run<8, 2>(SHC, XP, 528, kofs8, q16, c0hi, c0lo,
                            8, w * 2, 1, okc, py0, px0, acc2, lane);
        #pragma unroll
        for (int ii = 0; ii < 2; ++ii) {
            f32x4 bb = *(const f32x4*)(b_c0 + (w * 2 + ii) * 16 + q * 4);
            int chB = ((w * 2 + ii) * 16 + q * 4) * 2;
            #pragma unroll
            for (int n = 0; n < 4; ++n) if (okc[n]) {
                int p = n * 16 + l15;
                f16x4 h;
                #pragma unroll
                for (int r = 0; r < 4; ++r)
                    h[r] = (_Float16)fmaxf(acc2[ii][n][r] + bb[r], 0.f);
                *(f16x4*)(SHC + XF + p * 264 + chB) = h;
            }
        }
    }
    __syncthreads();                       // XF visible; XP dead

    // conv1: M=128, K=128, XF -> XF2 (XF2 lives in XP's old bytes)
    {
        f32x4 acc2[2][4];
        #pragma unroll
        for (int ii = 0; ii < 2; ++ii)
            #pragma unroll
            for (int n = 0; n < 4; ++n) acc2[ii][n] = (f32x4){0.f, 0.f, 0.f, 0.f};
        conv_mfma_run<4, 2>(SHC, XF, 264, kofs4, q16, c1hi, c1lo,
                            8, w * 2, 1, okc, py0, px0, acc2, lane);
        #pragma unroll
        for (int ii = 0; ii < 2; ++ii) {
            f32x4 bb = *(const f32x4*)(b_c1 + (w * 2 + ii) * 16 + q * 4);
            int chB = ((w * 2 + ii) * 16 + q * 4) * 2;
            #pragma unroll
            for (int n = 0; n < 4; ++n) if (okc[n]) {
                int p = n * 16 + l15;
                f16x4 h;
                #pragma unroll
                for (int r = 0; r < 4; ++r)
                    h[r] = (_Float16)fmaxf(acc2[ii][n][r] + bb[r], 0.f);
                *(f16x4*)(SHC + XF2 + p * 264 + chB) = h;
            }
        }
    }
    __syncthreads();                       // XF2 visible; XF dead

    // static gates: st = conv_cs(x_feat) + (cx0b+ch0b) + v_first window.
    // Finalized in registers; stored to ST (f16) only after a barrier, since
    // ST aliases XF2.
    const int fv = firstv[s];
    {
        f32x4 acc[4][4];
        #pragma unroll
        for (int g = 0; g < 4; ++g)
            #pragma unroll
            for (int n = 0; n < 4; ++n) acc[g][n] = (f32x4){0.f, 0.f, 0.f, 0.f};
        conv_mfma_run<4, 4>(SHC, XF2, 264, kofs4, q16, cshi, cslo,
                            16, w, 4, okc, py0, px0, acc, lane);
        const int fy = fv / 7, fx = fv % 7;
        #pragma unroll
        for (int g = 0; g < 4; ++g) {
            int m0 = g * 64 + w * 16 + q * 4;
            f32x4 b0 = *(const f32x4*)(cx0b + m0);
            f32x4 bh = *(const f32x4*)(ch0b + m0);
            #pragma unroll
            for (int n = 0; n < 4; ++n) {
                acc[g][n] += b0 + bh;
                int dy = fy - py0[n], dx = fx - px0[n];
                if (okc[n] && dy >= -1 && dy <= 1 && dx >= -1 && dx <= 1) {
                    int tap = (dy + 1) * 3 + (dx + 1);
                    acc[g][n] += *(const f32x4*)(wv1 + tap * 256 + m0);
                }
            }
        }
        __syncthreads();                   // ALL waves' XF2 reads done; safe to write ST
        #pragma unroll
        for (int g = 0; g < 4; ++g) {
            int m0 = g * 64 + w * 16 + q * 4;
            #pragma unroll
            for (int n = 0; n < 4; ++n) if (okc[n]) {
                int p = n * 16 + l15;
                f16x4 h;
                #pragma unroll
                for (int r = 0; r < 4; ++r) h[r] = (_Float16)acc[g][n][r];
                *(f16x4*)(SHC + ST + p * STSTR + m0 * 2) = h;
            }
        }
    }
    // zero PL (aliases XF, dead) + init preds: vp1 = v_first, vp2 = empty(49)
    for (int i = tid; i < 12936 / 4; i += 256) SHf[i] = 0.f;
    if (tid == 0) { ((int*)(SHC + PRD))[0] = fv; ((int*)(SHC + PRD))[1] = 49; }
    __syncthreads();                       // ST, PL, PRD visible

    // layer-1 biases cached in registers
    f32x4 b1[4];
    #pragma unroll
    for (int g = 0; g < 4; ++g) {
        int m0 = g * 64 + w * 16 + q * 4;
        b1[g] = *(const f32x4*)(cx1b + m0) + *(const f32x4*)(ch1b + m0);
    }

    float c0s[4][4], c1s[4][4];
    #pragma unroll
    for (int n = 0; n < 4; ++n)
        #pragma unroll
        for (int r = 0; r < 4; ++r) { c0s[n][r] = 0.f; c1s[n][r] = 0.f; }

    float* outS = out + (size_t)s * 450;

    // ============ PHASE B: 9 recurrent steps ============
    for (int t = 0; t < 9; ++t) {
        f32x4 acc[4][4];
        // ---- L0 gates: acc = ST (f16->f32) + vp1/vp2 injections; conv over h0 (K=64) ----
        #pragma unroll
        for (int g = 0; g < 4; ++g) {
            int m0 = g * 64 + w * 16 + q * 4;
            #pragma unroll
            for (int n = 0; n < 4; ++n) {
                int p = okc[n] ? (n * 16 + l15) : 0;
                f16x4 hv = *(const f16x4*)(SHC + ST + p * STSTR + m0 * 2);
                acc[g][n] = (f32x4){(float)hv[0], (float)hv[1], (float)hv[2], (float)hv[3]};
            }
        }
        {
            int p1 = ((const int*)(SHC + PRD))[0];
            int p2 = ((const int*)(SHC + PRD))[1];
            inject_onehot(acc, wvp1, p1, okc, py0, px0, w, q);
            inject_onehot(acc, wvp2, p2, okc, py0, px0, w, q);
        }
        conv_mfma_run<2, 4, false>(SHC, PL, 264, kofs2, q16, g0hi, g0lo,
                                   16, w, 4, okc, py0, px0, acc, lane);
        __syncthreads();                   // L0 reads of h0 done
        {   // L0 LSTM epilogue (in-lane), write h0 f16
            int chB = (w * 16 + q * 4) * 2;
            #pragma unroll
            for (int n = 0; n < 4; ++n) if (okc[n]) {
                int p = n * 16 + l15;
                f16x4 h;
                #pragma unroll
                for (int r = 0; r < 4; ++r) {
                    float ig = sigmoidf_(acc[0][n][r]);
                    float fg = sigmoidf_(acc[1][n][r]);
                    float gg = tanhf(acc[2][n][r]);
                    float og = sigmoidf_(acc[3][n][r]);
                    float cy = fg * c0s[n][r] + ig * gg;
                    c0s[n][r] = cy;
                    h[r] = (_Float16)(og * tanhf(cy));
                }
                *(f16x4*)(SHC + PL + p * 264 + chB) = h;
            }
        }
        __syncthreads();                   // h0 visible
        // ---- L1 gates: K = [h0 new | h1 old] = PL ch 0..127 ----
        #pragma unroll
        for (int g = 0; g < 4; ++g)
            #pragma unroll
            for (int n = 0; n < 4; ++n) acc[g][n] = b1[g];
        conv_mfma_run<4, 4, false>(SHC, PL, 264, kofs4, q16, g1hi, g1lo,
                                   16, w, 4, okc, py0, px0, acc, lane);
        __syncthreads();                   // L1 reads of h1-old done
        {   // L1 LSTM epilogue, write h1 f16
            int chB = 128 + (w * 16 + q * 4) * 2;
            #pragma unroll
            for (int n = 0; n < 4; ++n) if (okc[n]) {
                int p = n * 16 + l15;
                f16x4 h;
                #pragma unroll
                for (int r = 0; r < 4; ++r) {
                    float ig = sigmoidf_(acc[0][n][r]);
                    float fg = sigmoidf_(acc[1][n][r]);
                    float gg = tanhf(acc[2][n][r]);
                    float og = sigmoidf_(acc[3][n][r]);
                    float cy = fg * c1s[n][r] + ig * gg;
                    c1s[n][r] = cy;
                    h[r] = (_Float16)(og * tanhf(cy));
                }
                *(f16x4*)(SHC + PL + p * 264 + chB) = h;
            }
        }
        __syncthreads();                   // h1 visible (fc input)
        {   // fc via MFMA: M=64 (50 live), K=3136 from PL h1; col 0 live
            f32x4 afc[4];
            #pragma unroll
            for (int mi = 0; mi < 4; ++mi) afc[mi] = (f32x4){0.f, 0.f, 0.f, 0.f};
            int kc0 = w * 25;
            int kcN = (w < 3) ? 25 : 23;
            #pragma unroll 1
            for (int kc = 0; kc < kcN; ++kc) {
                int kg = kc0 + kc;
                int aB = (l15 == 0) ? (PL + (kg >> 1) * 264 + 128 + (kg & 1) * 64 + q16) : Z512;
                f16x8 B = *(const f16x8*)(SHC + aB);
                #pragma unroll
                for (int mi = 0; mi < 4; ++mi) {
                    int frag = ((kg * 4 + mi) << 9) + lane * 8;
                    f16x8 Ah = *(const f16x8*)(fchi + frag);
                    f16x8 Al = *(const f16x8*)(fclo + frag);
                    afc[mi] = __builtin_amdgcn_mfma_f32_16x16x32_f16(Al, B, afc[mi], 0, 0, 0);
                    afc[mi] = __builtin_amdgcn_mfma_f32_16x16x32_f16(Ah, B, afc[mi], 0, 0, 0);
                }
            }
            if (l15 == 0) {
                #pragma unroll
                for (int mi = 0; mi < 4; ++mi)
                    *(f32x4*)(SHC + FCP + w * 256 + mi * 64 + q16) = afc[mi];
            }
        }
        __syncthreads();                   // fc partials visible
        if (tid < 64) {
            int c = tid;
            const float* fp = (const float*)(SHC + FCP);
            float lg = fp[c] + fp[64 + c] + fp[128 + c] + fp[192 + c];
            float v = -3.4e38f;
            if (c < 50) { lg += fcb[c]; outS[t * 50 + c] = lg; v = lg; }
            int idx = c;
            #pragma unroll
            for (int off = 1; off < 64; off <<= 1) {
                float ov = __shfl_xor(v, off, 64);
                int   oi = __shfl_xor(idx, off, 64);
                if (ov > v || (ov == v && oi < idx)) { v = ov; idx = oi; }
            }
            if (c == 0) {
                int* pr = (int*)(SHC + PRD);
                pr[1] = pr[0];             // vp2 <- vp1
                pr[0] = idx;               // vp1 <- one-hot(pred)
            }
        }
        __syncthreads();                   // PRD visible; FCP reusable
    }
}

// ================= weight repack kernels =================
// OIHW conv weights -> A fragments [tap][kc][mi][lane][8], hi/lo f16 split
__global__ void repack_frags_k(const float* __restrict__ w, _Float16* __restrict__ ohi,
                               _Float16* __restrict__ olo, int ICS, int KMAX,
                               int NKC, int NMF, int total) {
    int i = blockIdx.x * 256 + threadIdx.x;
    if (i >= total) return;
    int j = i & 7, lane = (i >> 3) & 63;
    int rest = i >> 9;
    int mi = rest % NMF; rest /= NMF;
    int kc = rest % NKC; int tap = rest / NKC;
    int m = mi * 16 + (lane & 15);
    int k = kc * 32 + ((lane >> 4) & 3) * 8 + j;
    float v = (k < KMAX) ? w[((size_t)m * ICS + k) * 9 + tap] : 0.f;
    _Float16 hv = (_Float16)v;
    ohi[i] = hv; olo[i] = (_Float16)(v - (float)hv);
}

__global__ void repack_g1_k(const float* __restrict__ cx1w, const float* __restrict__ ch1w,
                            _Float16* __restrict__ ohi, _Float16* __restrict__ olo) {
    int i = blockIdx.x * 256 + threadIdx.x;
    if (i >= 294912) return;
    int j = i & 7; int lane = (i >> 3) & 63; int mt = (i >> 9) & 15;
    int rest = i >> 13; int kc = rest & 3; int tap = rest >> 2;
    int m = mt * 16 + (lane & 15);
    int kk = (lane >> 4) * 8 + j;
    float wv;
    if (kc < 2) wv = cx1w[((size_t)m * 64 + kc * 32 + kk) * 9 + tap];
    else        wv = ch1w[((size_t)m * 64 + (kc - 2) * 32 + kk) * 9 + tap];
    _Float16 hv = (_Float16)wv;
    ohi[i] = hv; olo[i] = (_Float16)(wv - (float)hv);
}

// fc weights [50][3136] -> frags [kc 98][mi 4][lane][8], k = p*64+ch
__global__ void repack_fc_k(const float* __restrict__ fcw, _Float16* __restrict__ ohi,
                            _Float16* __restrict__ olo) {
    int i = blockIdx.x * 256 + threadIdx.x;
    if (i >= 200704) return;
    int j = i & 7, lane = (i >> 3) & 63;
    int rest = i >> 9;
    int mi = rest & 3, kc = rest >> 2;
    int cls = mi * 16 + (lane & 15);
    int k = kc * 32 + ((lane >> 4) & 3) * 8 + j;
    int ch = k & 63, p = k >> 6;
    float v = (cls < 50) ? fcw[(size_t)cls * 3136 + ch * 49 + p] : 0.f;
    _Float16 hv = (_Float16)v;
    ohi[i] = hv; olo[i] = (_Float16)(v - (float)hv);
}

// one-hot conv tables: wv[tap][m] = cx0w[m, ic, tap]
__global__ void repack_wv_k(const float* __restrict__ cx0w, float* __restrict__ o, int ic) {
    int i = blockIdx.x * 256 + threadIdx.x;
    if (i >= 2304) return;
    int tap = i / 256, m = i % 256;
    o[i] = cx0w[((size_t)m * 131 + ic) * 9 + tap];
}

extern "C" void kernel_launch(void* const* d_in, const int* in_sizes, int n_in,
                              void* d_out, int out_size, void* d_ws, size_t ws_size,
                              hipStream_t stream)
{
    const float* x     = (const float*)d_in[0];
    const int*   fv    = (const int*)  d_in[1];
    const float* c0w   = (const float*)d_in[2];
    const float* c0b   = (const float*)d_in[3];
    const float* c1w   = (const float*)d_in[4];
    const float* c1b   = (const float*)d_in[5];
    const float* cx0w  = (const float*)d_in[6];
    const float* cx0b  = (const float*)d_in[7];
    const float* ch0w  = (const float*)d_in[8];
    const float* ch0b  = (const float*)d_in[9];
    const float* cx1w  = (const float*)d_in[10];
    const float* cx1b  = (const float*)d_in[11];
    const float* ch1w  = (const float*)d_in[12];
    const float* ch1b  = (const float*)d_in[13];
    const float* fcw   = (const float*)d_in[14];
    const float* fcb   = (const float*)d_in[15];
    float* out = (float*)d_out;
    const int n = in_sizes[0] / 12544;

    _Float16* h = (_Float16*)d_ws;
    _Float16* g0hi = h;                  // 147456 (NKC=2, NMF=16)
    _Float16* g0lo = g0hi + 147456;
    _Float16* g1hi = g0lo + 147456;      // 294912
    _Float16* g1lo = g1hi + 294912;
    _Float16* c0hi = g1lo + 294912;      // 294912
    _Float16* c0lo = c0hi + 294912;
    _Float16* c1hi = c0lo + 294912;      // 147456
    _Float16* c1lo = c1hi + 147456;
    _Float16* cshi = c1lo + 147456;      // 294912
    _Float16* cslo = cshi + 294912;
    _Float16* fchi = cslo + 294912;      // 200704
    _Float16* fclo = fchi + 200704;
    float*    wv1  = (float*)(fclo + 200704);   // 2304 f32 each
    float*    wvp1 = wv1 + 2304;
    float*    wvp2 = wvp1 + 2304;

    repack_frags_k<<<(147456 + 255) / 256, 256, 0, stream>>>(ch0w, g0hi, g0lo, 64, 64, 2, 16, 147456);
    repack_g1_k   <<<(294912 + 255) / 256, 256, 0, stream>>>(cx1w, ch1w, g1hi, g1lo);
    repack_frags_k<<<(294912 + 255) / 256, 256, 0, stream>>>(c0w, c0hi, c0lo, 256, 256, 8, 8, 294912);
    repack_frags_k<<<(147456 + 255) / 256, 256, 0, stream>>>(c1w, c1hi, c1lo, 128, 128, 4, 8, 147456);
    repack_frags_k<<<(294912 + 255) / 256, 256, 0, stream>>>(cx0w, cshi, cslo, 131, 128, 4, 16, 294912);
    repack_fc_k   <<<(200704 + 255) / 256, 256, 0, stream>>>(fcw, fchi, fclo);
    repack_wv_k   <<<(2304 + 255) / 256, 256, 0, stream>>>(cx0w, wv1, 130);
    repack_wv_k   <<<(2304 + 255) / 256, 256, 0, stream>>>(cx0w, wvp1, 129);
    repack_wv_k   <<<(2304 + 255) / 256, 256, 0, stream>>>(cx0w, wvp2, 128);

    (void)hipFuncSetAttribute((const void*)poly_fused,
                              hipFuncAttributeMaxDynamicSharedMemorySize, LDSB);
    poly_fused<<<n, 256, LDSB, stream>>>(x, fv, c0b, c1b, cx0b, ch0b, cx1b, ch1b, fcb,
                                         c0hi, c0lo, c1hi, c1lo, cshi, cslo,
                                         g0hi, g0lo, g1hi, g1lo, fchi, fclo,
                                         wv1, wvp1, wvp2, out);
}

// Round 6
// 2562.479 us; speedup vs baseline: 2.7035x; 1.1030x over previous
//
#include <hip/hip_runtime.h>
#include <hip/hip_fp16.h>

typedef float f32x4 __attribute__((ext_vector_type(4)));
typedef _Float16 f16x8 __attribute__((ext_vector_type(8)));
typedef _Float16 f16x4 __attribute__((ext_vector_type(4)));

// ---------------- LDS byte map ----------------
// Occupancy is register-bound at 2 waves/SIMD (r0-r4: kernel needs ~128 arch
// regs; launch_bounds(256,3/4) caps arch at 84/64 -> scratch spill). So this
// round cuts the per-wave serial path instead:
//  - h-plane DOUBLE BUFFER (PL0/PL1): h0new/h1new written to the *other*
//    buffer -> no "reads-done" barriers. 6 -> 3 barriers per step.
//  - redundant per-wave argmax from FCP (deterministic) -> pred in registers,
//    no PRD round-trip, kills another barrier.
//  - fast sigmoid/tanh via v_exp_f32/v_rcp_f32 (libm tanhf/expf was the
//    dominant VALU term: 45 transcendentals/lane/step).
// Layout (53 KB, 2 blocks/CU = 106 KB <= 160 KB):
//   PL0 @0     [49][264]: h0 ch0..63 (byte 0..127), h1 (128..255)
//   PL1 @12960 same (ping-pong buffer)
//   ST  @25904 [49][528] static gates f16, persists phase B
//   FCP @51792 1 KiB fc partials;  Z512 @52816 zeros (OOB fallback)
// Phase A aliasing: XP (x staged [49][528]) @25904 (=ST, dies after conv0);
//   XF (conv0 out) @PL0; XF2 (conv1 out) @PL1. ST no longer aliases XF2, so
//   static gates write directly (no register staging / extra barrier);
//   PL0 re-zeroed during the static phase (h0old/h1old = 0 at t=0).
#define PL0   0
#define PL1   12960
#define STb   25904
#define STSTR 528
#define XPb   25904
#define XFb   0
#define XF2b  12960
#define FCP   51792
#define Z512  52816
#define LDSB  53328

// fast transcendentals: v_exp_f32 (2^x) + v_rcp_f32. Saturation exact at
// +/-inf (rcp(inf)=0). ~1e-7 rel error, drowned by f16 activation storage.
__device__ __forceinline__ float fexp_(float x) {
    return __builtin_amdgcn_exp2f(x * 1.44269504f);
}
__device__ __forceinline__ float sigmoidf_(float v) {
    return __builtin_amdgcn_rcpf(1.0f + fexp_(-v));
}
__device__ __forceinline__ float tanhf_(float v) {
    float e = fexp_(2.0f * v);
    return 1.0f - 2.0f * __builtin_amdgcn_rcpf(e + 1.0f);
}

// shifted-window conv GEMM, weights f16 (A), acts single f16 (B):
// HILO=true: acc += Al*B + Ah*B (hi/lo split ~f32-accurate weights).
// HILO=false: acc += Ah*B (single f16; halves MFMAs and A-loads).
// Tap loop deliberately NOT unrolled: keeps the scheduling window small so
// the allocator doesn't hoist 9 taps' worth of loads and spill acc.
template <int NKC, int NMI, bool HILO = true>
__device__ __forceinline__ void conv_mfma_run(
    const char* __restrict__ SHb, int baseB, int pstr2,
    const int (&kofs)[NKC], int q16,
    const _Float16* __restrict__ ghi, const _Float16* __restrict__ glo,
    int NMF, int miBase, int miStep,
    const int (&okc)[4], const int (&py0)[4], const int (&px0)[4],
    f32x4 (&acc)[NMI][4], int lane)
{
    #pragma unroll 1
    for (int tap = 0; tap < 9; ++tap) {
        const int dy = tap / 3 - 1, dx = tap % 3 - 1;
        int bb[4];
        #pragma unroll
        for (int n = 0; n < 4; ++n) {
            int py = py0[n] + dy, px = px0[n] + dx;
            bool ok = okc[n] && ((unsigned)py < 7u) && ((unsigned)px < 7u);
            bb[n] = ok ? baseB + (py * 7 + px) * pstr2 : Z512;  // Z512+kof+16 <= Z512+512: zeros
        }
        #pragma unroll
        for (int kc = 0; kc < NKC; ++kc) {
            const int kof = kofs[kc] + q16;
            f16x8 B[4];
            #pragma unroll
            for (int n = 0; n < 4; ++n) B[n] = *(const f16x8*)(SHb + bb[n] + kof);
            #pragma unroll
            for (int ii = 0; ii < NMI; ++ii) {
                int frag = (((tap * NKC + kc) * NMF + (miBase + ii * miStep)) << 9) + lane * 8;
                f16x8 Ah = *(const f16x8*)(ghi + frag);
                if constexpr (HILO) {
                    f16x8 Al = *(const f16x8*)(glo + frag);
                    #pragma unroll
                    for (int n = 0; n < 4; ++n) {
                        acc[ii][n] = __builtin_amdgcn_mfma_f32_16x16x32_f16(Al, B[n], acc[ii][n], 0, 0, 0);
                        acc[ii][n] = __builtin_amdgcn_mfma_f32_16x16x32_f16(Ah, B[n], acc[ii][n], 0, 0, 0);
                    }
                } else {
                    #pragma unroll
                    for (int n = 0; n < 4; ++n)
                        acc[ii][n] = __builtin_amdgcn_mfma_f32_16x16x32_f16(Ah, B[n], acc[ii][n], 0, 0, 0);
                }
            }
        }
    }
}

// one-hot map conv contribution injected at acc-init (map one-hot at pixel pv)
__device__ __forceinline__ void inject_onehot(
    f32x4 (&acc)[4][4], const float* __restrict__ wv, int pv,
    const int (&okc)[4], const int (&py0)[4], const int (&px0)[4], int w, int q)
{
    if (pv >= 49) return;                 // EOS / empty map
    int vy = pv / 7, vx = pv % 7;
    #pragma unroll
    for (int n = 0; n < 4; ++n) {
        int dy = vy - py0[n], dx = vx - px0[n];
        if (okc[n] && dy >= -1 && dy <= 1 && dx >= -1 && dx <= 1) {
            int tap = (dy + 1) * 3 + (dx + 1);
            const float* wp = wv + tap * 256 + w * 16 + q * 4;
            #pragma unroll
            for (int g = 0; g < 4; ++g)
                acc[g][n] += *(const f32x4*)(wp + g * 64);
        }
    }
}

extern "C" __global__ __launch_bounds__(256, 2)
void poly_fused(const float* __restrict__ x, const int* __restrict__ firstv,
                const float* __restrict__ b_c0, const float* __restrict__ b_c1,
                const float* __restrict__ cx0b, const float* __restrict__ ch0b,
                const float* __restrict__ cx1b, const float* __restrict__ ch1b,
                const float* __restrict__ fcb,
                const _Float16* __restrict__ c0hi, const _Float16* __restrict__ c0lo,
                const _Float16* __restrict__ c1hi, const _Float16* __restrict__ c1lo,
                const _Float16* __restrict__ cshi, const _Float16* __restrict__ cslo,
                const _Float16* __restrict__ g0hi, const _Float16* __restrict__ g0lo,
                const _Float16* __restrict__ g1x, const _Float16* __restrict__ g1h,
                const _Float16* __restrict__ fchi, const _Float16* __restrict__ fclo,
                const float* __restrict__ wv1,
                const float* __restrict__ wvp1, const float* __restrict__ wvp2,
                float* __restrict__ out)
{
    extern __shared__ char SHC[];
    float* SHf = (float*)SHC;
    const int tid = threadIdx.x, s = blockIdx.x;
    const int lane = tid & 63, w = tid >> 6;
    const int q = lane >> 4, l15 = lane & 15, q16 = q * 16;

    for (int i = tid; i < LDSB / 4; i += 256) SHf[i] = 0.f;
    __syncthreads();

    // per-lane column geometry (col = n*16 + l15; 49 live pixels)
    int okc[4], py0[4], px0[4];
    #pragma unroll
    for (int n = 0; n < 4; ++n) {
        int col = n * 16 + l15;
        okc[n] = col < 49;
        int p = okc[n] ? col : 0;
        py0[n] = p / 7; px0[n] = p % 7;
    }

    // ============ PHASE A ============
    const float* xs = x + (size_t)s * 12544;
    for (int e = tid; e < 12544; e += 256) {
        int ch = e / 49, p = e - ch * 49;
        *(_Float16*)(SHC + XPb + p * 528 + ch * 2) = (_Float16)xs[e];
    }
    __syncthreads();                       // XP visible

    const int kofs8[8] = {0, 64, 128, 192, 256, 320, 384, 448};
    const int kofs4[4] = {0, 64, 128, 192};
    const int kofs2[2] = {0, 64};
    const int kofs2h[2] = {128, 192};

    // conv0: M=128 (8 mfrags; wave owns w*2, w*2+1), K=256; XP -> XF(@PL0)
    {
        f32x4 acc2[2][4];
        #pragma unroll
        for (int ii = 0; ii < 2; ++ii)
            #pragma unroll
            for (int n = 0; n < 4; ++n) acc2[ii][n] = (f32x4){0.f, 0.f, 0.f, 0.f};
        conv_mfma_run<8, 2>(SHC, XPb, 528, kofs8, q16, c0hi, c0lo,
                            8, w * 2, 1, okc, py0, px0, acc2, lane);
        #pragma unroll
        for (int ii = 0; ii < 2; ++ii) {
            f32x4 bb = *(const f32x4*)(b_c0 + (w * 2 + ii) * 16 + q * 4);
            int chB = ((w * 2 + ii) * 16 + q * 4) * 2;
            #pragma unroll
            for (int n = 0; n < 4; ++n) if (okc[n]) {
                int p = n * 16 + l15;
                f16x4 h;
                #pragma unroll
                for (int r = 0; r < 4; ++r)
                    h[r] = (_Float16)fmaxf(acc2[ii][n][r] + bb[r], 0.f);
                *(f16x4*)(SHC + XFb + p * 264 + chB) = h;
            }
        }
    }
    __syncthreads();                       // XF visible; XP dead

    // conv1: M=128, K=128, XF -> XF2(@PL1)
    {
        f32x4 acc2[2][4];
        #pragma unroll
        for (int ii = 0; ii < 2; ++ii)
            #pragma unroll
            for (int n = 0; n < 4; ++n) acc2[ii][n] = (f32x4){0.f, 0.f, 0.f, 0.f};
        conv_mfma_run<4, 2>(SHC, XFb, 264, kofs4, q16, c1hi, c1lo,
                            8, w * 2, 1, okc, py0, px0, acc2, lane);
        #pragma unroll
        for (int ii = 0; ii < 2; ++ii) {
            f32x4 bb = *(const f32x4*)(b_c1 + (w * 2 + ii) * 16 + q * 4);
            int chB = ((w * 2 + ii) * 16 + q * 4) * 2;
            #pragma unroll
            for (int n = 0; n < 4; ++n) if (okc[n]) {
                int p = n * 16 + l15;
                f16x4 h;
                #pragma unroll
                for (int r = 0; r < 4; ++r)
                    h[r] = (_Float16)fmaxf(acc2[ii][n][r] + bb[r], 0.f);
                *(f16x4*)(SHC + XF2b + p * 264 + chB) = h;
            }
        }
    }
    __syncthreads();                       // XF2 visible; XF dead

    // static gates: st = conv_cs(x_feat) + (cx0b+ch0b) + v_first window.
    // Writes ST (@XP's dead bytes) directly — disjoint from XF2 being read.
    // PL0 (=XF, dead) re-zeroed in the same phase: h0old/h1old = 0 at t=0.
    const int fv = firstv[s];
    {
        f32x4 acc[4][4];
        #pragma unroll
        for (int g = 0; g < 4; ++g)
            #pragma unroll
            for (int n = 0; n < 4; ++n) acc[g][n] = (f32x4){0.f, 0.f, 0.f, 0.f};
        conv_mfma_run<4, 4>(SHC, XF2b, 264, kofs4, q16, cshi, cslo,
                            16, w, 4, okc, py0, px0, acc, lane);
        const int fy = fv / 7, fx = fv % 7;
        #pragma unroll
        for (int g = 0; g < 4; ++g) {
            int m0 = g * 64 + w * 16 + q * 4;
            f32x4 b0 = *(const f32x4*)(cx0b + m0);
            f32x4 bh = *(const f32x4*)(ch0b + m0);
            #pragma unroll
            for (int n = 0; n < 4; ++n) {
                acc[g][n] += b0 + bh;
                int dy = fy - py0[n], dx = fx - px0[n];
                if (okc[n] && dy >= -1 && dy <= 1 && dx >= -1 && dx <= 1) {
                    int tap = (dy + 1) * 3 + (dx + 1);
                    acc[g][n] += *(const f32x4*)(wv1 + tap * 256 + m0);
                }
                if (okc[n]) {
                    int p = n * 16 + l15;
                    f16x4 h;
                    #pragma unroll
                    for (int r = 0; r < 4; ++r) h[r] = (_Float16)acc[g][n][r];
                    *(f16x4*)(SHC + STb + p * STSTR + m0 * 2) = h;
                }
            }
        }
    }
    for (int i = tid; i < 12936 / 4; i += 256) SHf[i] = 0.f;   // zero PL0
    __syncthreads();                       // ST + PL0 zeros visible

    // layer-1 biases cached in registers
    f32x4 b1[4];
    #pragma unroll
    for (int g = 0; g < 4; ++g) {
        int m0 = g * 64 + w * 16 + q * 4;
        b1[g] = *(const f32x4*)(cx1b + m0) + *(const f32x4*)(ch1b + m0);
    }

    float c0s[4][4], c1s[4][4];
    #pragma unroll
    for (int n = 0; n < 4; ++n)
        #pragma unroll
        for (int r = 0; r < 4; ++r) { c0s[n][r] = 0.f; c1s[n][r] = 0.f; }

    float* outS = out + (size_t)s * 450;
    int p1 = fv, p2 = 49;                  // preds live in registers

    // ============ PHASE B: 9 recurrent steps, 3 barriers each ============
    for (int t = 0; t < 9; ++t) {
        const int cur = (t & 1) ? PL1 : PL0;
        const int nxt = (t & 1) ? PL0 : PL1;
        f32x4 acc[4][4];
        // ---- L0 gates: acc = ST + vp injections; conv over h0old (cur) ----
        #pragma unroll
        for (int g = 0; g < 4; ++g) {
            int m0 = g * 64 + w * 16 + q * 4;
            #pragma unroll
            for (int n = 0; n < 4; ++n) {
                int p = okc[n] ? (n * 16 + l15) : 0;
                f16x4 hv = *(const f16x4*)(SHC + STb + p * STSTR + m0 * 2);
                acc[g][n] = (f32x4){(float)hv[0], (float)hv[1], (float)hv[2], (float)hv[3]};
            }
        }
        inject_onehot(acc, wvp1, p1, okc, py0, px0, w, q);
        inject_onehot(acc, wvp2, p2, okc, py0, px0, w, q);
        conv_mfma_run<2, 4, false>(SHC, cur, 264, kofs2, q16, g0hi, g0hi,
                                   16, w, 4, okc, py0, px0, acc, lane);
        {   // L0 LSTM epilogue, write h0new -> nxt (no barrier needed first)
            int chB = (w * 16 + q * 4) * 2;
            #pragma unroll
            for (int n = 0; n < 4; ++n) if (okc[n]) {
                int p = n * 16 + l15;
                f16x4 h;
                #pragma unroll
                for (int r = 0; r < 4; ++r) {
                    float ig = sigmoidf_(acc[0][n][r]);
                    float fg = sigmoidf_(acc[1][n][r]);
                    float gg = tanhf_(acc[2][n][r]);
                    float og = sigmoidf_(acc[3][n][r]);
                    float cy = fg * c0s[n][r] + ig * gg;
                    c0s[n][r] = cy;
                    h[r] = (_Float16)(og * tanhf_(cy));
                }
                *(f16x4*)(SHC + nxt + p * 264 + chB) = h;
            }
        }
        __syncthreads();                   // [1] h0new visible
        // ---- L1 gates: K = [h0new (nxt) | h1old (cur)] ----
        #pragma unroll
        for (int g = 0; g < 4; ++g)
            #pragma unroll
            for (int n = 0; n < 4; ++n) acc[g][n] = b1[g];
        conv_mfma_run<2, 4, false>(SHC, nxt, 264, kofs2, q16, g1x, g1x,
                                   16, w, 4, okc, py0, px0, acc, lane);
        conv_mfma_run<2, 4, false>(SHC, cur, 264, kofs2h, q16, g1h, g1h,
                                   16, w, 4, okc, py0, px0, acc, lane);
        {   // L1 LSTM epilogue, write h1new -> nxt+128 (disjoint from reads)
            int chB = 128 + (w * 16 + q * 4) * 2;
            #pragma unroll
            for (int n = 0; n < 4; ++n) if (okc[n]) {
                int p = n * 16 + l15;
                f16x4 h;
                #pragma unroll
                for (int r = 0; r < 4; ++r) {
                    float ig = sigmoidf_(acc[0][n][r]);
                    float fg = sigmoidf_(acc[1][n][r]);
                    float gg = tanhf_(acc[2][n][r]);
                    float og = sigmoidf_(acc[3][n][r]);
                    float cy = fg * c1s[n][r] + ig * gg;
                    c1s[n][r] = cy;
                    h[r] = (_Float16)(og * tanhf_(cy));
                }
                *(f16x4*)(SHC + nxt + p * 264 + chB) = h;
            }
        }
        __syncthreads();                   // [2] h1new visible (fc input)
        {   // fc via MFMA: M=64 (50 live), K=3136 from nxt h1; col 0 live
            f32x4 afc[4];
            #pragma unroll
            for (int mi = 0; mi < 4; ++mi) afc[mi] = (f32x4){0.f, 0.f, 0.f, 0.f};
            int kc0 = w * 25;
            int kcN = (w < 3) ? 25 : 23;
            #pragma unroll 1
            for (int kc = 0; kc < kcN; ++kc) {
                int kg = kc0 + kc;
                int aB = (l15 == 0) ? (nxt + (kg >> 1) * 264 + 128 + (kg & 1) * 64 + q16) : Z512;
                f16x8 B = *(const f16x8*)(SHC + aB);
                #pragma unroll
                for (int mi = 0; mi < 4; ++mi) {
                    int frag = ((kg * 4 + mi) << 9) + lane * 8;
                    f16x8 Ah = *(const f16x8*)(fchi + frag);
                    f16x8 Al = *(const f16x8*)(fclo + frag);
                    afc[mi] = __builtin_amdgcn_mfma_f32_16x16x32_f16(Al, B, afc[mi], 0, 0, 0);
                    afc[mi] = __builtin_amdgcn_mfma_f32_16x16x32_f16(Ah, B, afc[mi], 0, 0, 0);
                }
            }
            if (l15 == 0) {
                #pragma unroll
                for (int mi = 0; mi < 4; ++mi)
                    *(f32x4*)(SHC + FCP + w * 256 + mi * 64 + q16) = afc[mi];
            }
        }
        __syncthreads();                   // [3] fc partials visible
        // redundant per-wave argmax (identical in all waves; pred stays in regs)
        {
            const float* fp = (const float*)(SHC + FCP);
            int c = lane;
            float lg = fp[c] + fp[64 + c] + fp[128 + c] + fp[192 + c];
            float v = -3.4e38f;
            if (c < 50) { lg += fcb[c]; v = lg; }
            if (w == 0 && c < 50) outS[t * 50 + c] = lg;
            int idx = c;
            #pragma unroll
            for (int off = 1; off < 64; off <<= 1) {
                float ov = __shfl_xor(v, off, 64);
                int   oi = __shfl_xor(idx, off, 64);
                if (ov > v || (ov == v && oi < idx)) { v = ov; idx = oi; }
            }
            p2 = p1; p1 = idx;
        }
        // no barrier: next FCP write is 2 barriers away (safe), PL[cur]
        // overwrite happens after all waves pass barrier [1] of step t+1.
    }
}

// ================= weight repack kernels =================
// OIHW conv weights -> A fragments [tap][kc][mi][lane][8], hi/lo f16 split
__global__ void repack_frags_k(const float* __restrict__ w, _Float16* __restrict__ ohi,
                               _Float16* __restrict__ olo, int ICS, int KMAX,
                               int NKC, int NMF, int total) {
    int i = blockIdx.x * 256 + threadIdx.x;
    if (i >= total) return;
    int j = i & 7, lane = (i >> 3) & 63;
    int rest = i >> 9;
    int mi = rest % NMF; rest /= NMF;
    int kc = rest % NKC; int tap = rest / NKC;
    int m = mi * 16 + (lane & 15);
    int k = kc * 32 + ((lane >> 4) & 3) * 8 + j;
    float v = (k < KMAX) ? w[((size_t)m * ICS + k) * 9 + tap] : 0.f;
    _Float16 hv = (_Float16)v;
    ohi[i] = hv; olo[i] = (_Float16)(v - (float)hv);
}

// fc weights [50][3136] -> frags [kc 98][mi 4][lane][8], k = p*64+ch
__global__ void repack_fc_k(const float* __restrict__ fcw, _Float16* __restrict__ ohi,
                            _Float16* __restrict__ olo) {
    int i = blockIdx.x * 256 + threadIdx.x;
    if (i >= 200704) return;
    int j = i & 7, lane = (i >> 3) & 63;
    int rest = i >> 9;
    int mi = rest & 3, kc = rest >> 2;
    int cls = mi * 16 + (lane & 15);
    int k = kc * 32 + ((lane >> 4) & 3) * 8 + j;
    int ch = k & 63, p = k >> 6;
    float v = (cls < 50) ? fcw[(size_t)cls * 3136 + ch * 49 + p] : 0.f;
    _Float16 hv = (_Float16)v;
    ohi[i] = hv; olo[i] = (_Float16)(v - (float)hv);
}

// one-hot conv tables: wv[tap][m] = cx0w[m, ic, tap]
__global__ void repack_wv_k(const float* __restrict__ cx0w, float* __restrict__ o, int ic) {
    int i = blockIdx.x * 256 + threadIdx.x;
    if (i >= 2304) return;
    int tap = i / 256, m = i % 256;
    o[i] = cx0w[((size_t)m * 131 + ic) * 9 + tap];
}

extern "C" void kernel_launch(void* const* d_in, const int* in_sizes, int n_in,
                              void* d_out, int out_size, void* d_ws, size_t ws_size,
                              hipStream_t stream)
{
    const float* x     = (const float*)d_in[0];
    const int*   fv    = (const int*)  d_in[1];
    const float* c0w   = (const float*)d_in[2];
    const float* c0b   = (const float*)d_in[3];
    const float* c1w   = (const float*)d_in[4];
    const float* c1b   = (const float*)d_in[5];
    const float* cx0w  = (const float*)d_in[6];
    const float* cx0b  = (const float*)d_in[7];
    const float* ch0w  = (const float*)d_in[8];
    const float* ch0b  = (const float*)d_in[9];
    const float* cx1w  = (const float*)d_in[10];
    const float* cx1b  = (const float*)d_in[11];
    const float* ch1w  = (const float*)d_in[12];
    const float* ch1b  = (const float*)d_in[13];
    const float* fcw   = (const float*)d_in[14];
    const float* fcb   = (const float*)d_in[15];
    float* out = (float*)d_out;
    const int n = in_sizes[0] / 12544;

    _Float16* h = (_Float16*)d_ws;
    _Float16* g0hi = h;                  // 147456 (NKC=2, NMF=16)
    _Float16* g0lo = g0hi + 147456;
    _Float16* g1xhi = g0lo + 147456;     // 147456 (cx1, NKC=2)
    _Float16* g1xlo = g1xhi + 147456;
    _Float16* g1hhi = g1xlo + 147456;    // 147456 (ch1, NKC=2)
    _Float16* g1hlo = g1hhi + 147456;
    _Float16* c0hi = g1hlo + 147456;     // 294912
    _Float16* c0lo = c0hi + 294912;
    _Float16* c1hi = c0lo + 294912;      // 147456
    _Float16* c1lo = c1hi + 147456;
    _Float16* cshi = c1lo + 147456;      // 294912
    _Float16* cslo = cshi + 294912;
    _Float16* fchi = cslo + 294912;      // 200704
    _Float16* fclo = fchi + 200704;
    float*    wv1  = (float*)(fclo + 200704);   // 2304 f32 each
    float*    wvp1 = wv1 + 2304;
    float*    wvp2 = wvp1 + 2304;

    repack_frags_k<<<(147456 + 255) / 256, 256, 0, stream>>>(ch0w, g0hi, g0lo, 64, 64, 2, 16, 147456);
    repack_frags_k<<<(147456 + 255) / 256, 256, 0, stream>>>(cx1w, g1xhi, g1xlo, 64, 64, 2, 16, 147456);
    repack_frags_k<<<(147456 + 255) / 256, 256, 0, stream>>>(ch1w, g1hhi, g1hlo, 64, 64, 2, 16, 147456);
    repack_frags_k<<<(294912 + 255) / 256, 256, 0, stream>>>(c0w, c0hi, c0lo, 256, 256, 8, 8, 294912);
    repack_frags_k<<<(147456 + 255) / 256, 256, 0, stream>>>(c1w, c1hi, c1lo, 128, 128, 4, 8, 147456);
    repack_frags_k<<<(294912 + 255) / 256, 256, 0, stream>>>(cx0w, cshi, cslo, 131, 128, 4, 16, 294912);
    repack_fc_k   <<<(200704 + 255) / 256, 256, 0, stream>>>(fcw, fchi, fclo);
    repack_wv_k   <<<(2304 + 255) / 256, 256, 0, stream>>>(cx0w, wv1, 130);
    repack_wv_k   <<<(2304 + 255) / 256, 256, 0, stream>>>(cx0w, wvp1, 129);
    repack_wv_k   <<<(2304 + 255) / 256, 256, 0, stream>>>(cx0w, wvp2, 128);

    (void)hipFuncSetAttribute((const void*)poly_fused,
                              hipFuncAttributeMaxDynamicSharedMemorySize, LDSB);
    poly_fused<<<n, 256, LDSB, stream>>>(x, fv, c0b, c1b, cx0b, ch0b, cx1b, ch1b, fcb,
                                         c0hi, c0lo, c1hi, c1lo, cshi, cslo,
                                         g0hi, g0lo, g1xhi, g1hhi, fchi, fclo,
                                         wv1, wvp1, wvp2, out);
}

// Round 7
// 2467.641 us; speedup vs baseline: 2.8074x; 1.0384x over previous
//
#include <hip/hip_runtime.h>
#include <hip/hip_fp16.h>

typedef float f32x4 __attribute__((ext_vector_type(4)));
typedef _Float16 f16x8 __attribute__((ext_vector_type(8)));
typedef _Float16 f16x4 __attribute__((ext_vector_type(4)));

// ---------------- LDS byte map ----------------
// Occupancy is register-bound at 2 waves/SIMD (r0-r4). r6 cut barriers 6->3
// and VALU (fast transcendentals). Remaining stall: serialized A-frag L2
// loads vs dependent MFMAs in the unroll-1 loops (~50% idle).
// r7: (a) single-f16 weights EVERYWHERE (r5 proved lo-drop numerically free
// for gates; fc logit err ~8e-5 << tolerance) -> halves MFMAs + A-loads in
// phase A and fc; (b) fuse fc(t) with L0conv(t+1) in one loop between
// bar2/bar3 (independent chains overlap; one-hot injection commutes to
// post-argmax); (c) skip L0conv at t=0 (h0old=0).
// Layout (53 KB, 2 blocks/CU):
//   PL0 @0     [49][264]: h0 ch0..63 (byte 0..127), h1 (128..255)
//   PL1 @12960 same (ping-pong buffer)
//   ST  @25904 [49][528] static gates f16, persists phase B
//   FCP @51792 1 KiB fc partials;  Z512 @52816 zeros (OOB fallback)
// Phase A aliasing: XP @25904 (=ST, dies after conv0); XF @PL0; XF2 @PL1.
#define PL0   0
#define PL1   12960
#define STb   25904
#define STSTR 528
#define XPb   25904
#define XFb   0
#define XF2b  12960
#define FCP   51792
#define Z512  52816
#define LDSB  53328

// fast transcendentals: v_exp_f32 (2^x) + v_rcp_f32. Saturation exact at
// +/-inf (rcp(inf)=0). ~1e-7 rel error, drowned by f16 activation storage.
__device__ __forceinline__ float fexp_(float x) {
    return __builtin_amdgcn_exp2f(x * 1.44269504f);
}
__device__ __forceinline__ float sigmoidf_(float v) {
    return __builtin_amdgcn_rcpf(1.0f + fexp_(-v));
}
__device__ __forceinline__ float tanhf_(float v) {
    float e = fexp_(2.0f * v);
    return 1.0f - 2.0f * __builtin_amdgcn_rcpf(e + 1.0f);
}

// shifted-window conv GEMM, weights single f16 (A), acts f16 (B).
// Tap loop deliberately NOT unrolled: keeps the scheduling window small so
// the allocator doesn't hoist 9 taps' worth of loads and spill acc.
template <int NKC, int NMI>
__device__ __forceinline__ void conv_mfma_run(
    const char* __restrict__ SHb, int baseB, int pstr2,
    const int (&kofs)[NKC], int q16,
    const _Float16* __restrict__ g,
    int NMF, int miBase, int miStep,
    const int (&okc)[4], const int (&py0)[4], const int (&px0)[4],
    f32x4 (&acc)[NMI][4], int lane)
{
    #pragma unroll 1
    for (int tap = 0; tap < 9; ++tap) {
        const int dy = tap / 3 - 1, dx = tap % 3 - 1;
        int bb[4];
        #pragma unroll
        for (int n = 0; n < 4; ++n) {
            int py = py0[n] + dy, px = px0[n] + dx;
            bool ok = okc[n] && ((unsigned)py < 7u) && ((unsigned)px < 7u);
            bb[n] = ok ? baseB + (py * 7 + px) * pstr2 : Z512;  // Z512..+512: zeros
        }
        #pragma unroll
        for (int kc = 0; kc < NKC; ++kc) {
            const int kof = kofs[kc] + q16;
            f16x8 B[4];
            #pragma unroll
            for (int n = 0; n < 4; ++n) B[n] = *(const f16x8*)(SHb + bb[n] + kof);
            #pragma unroll
            for (int ii = 0; ii < NMI; ++ii) {
                int frag = (((tap * NKC + kc) * NMF + (miBase + ii * miStep)) << 9) + lane * 8;
                f16x8 Ah = *(const f16x8*)(g + frag);
                #pragma unroll
                for (int n = 0; n < 4; ++n)
                    acc[ii][n] = __builtin_amdgcn_mfma_f32_16x16x32_f16(Ah, B[n], acc[ii][n], 0, 0, 0);
            }
        }
    }
}

// one-hot map conv contribution injected into acc (map one-hot at pixel pv)
__device__ __forceinline__ void inject_onehot(
    f32x4 (&acc)[4][4], const float* __restrict__ wv, int pv,
    const int (&okc)[4], const int (&py0)[4], const int (&px0)[4], int w, int q)
{
    if (pv >= 49) return;                 // EOS / empty map
    int vy = pv / 7, vx = pv % 7;
    #pragma unroll
    for (int n = 0; n < 4; ++n) {
        int dy = vy - py0[n], dx = vx - px0[n];
        if (okc[n] && dy >= -1 && dy <= 1 && dx >= -1 && dx <= 1) {
            int tap = (dy + 1) * 3 + (dx + 1);
            const float* wp = wv + tap * 256 + w * 16 + q * 4;
            #pragma unroll
            for (int g = 0; g < 4; ++g)
                acc[g][n] += *(const f32x4*)(wp + g * 64);
        }
    }
}

extern "C" __global__ __launch_bounds__(256, 2)
void poly_fused(const float* __restrict__ x, const int* __restrict__ firstv,
                const float* __restrict__ b_c0, const float* __restrict__ b_c1,
                const float* __restrict__ cx0b, const float* __restrict__ ch0b,
                const float* __restrict__ cx1b, const float* __restrict__ ch1b,
                const float* __restrict__ fcb,
                const _Float16* __restrict__ c0hi,
                const _Float16* __restrict__ c1hi,
                const _Float16* __restrict__ cshi,
                const _Float16* __restrict__ g0hi,
                const _Float16* __restrict__ g1x, const _Float16* __restrict__ g1h,
                const _Float16* __restrict__ fchi,
                const float* __restrict__ wv1,
                const float* __restrict__ wvp1, const float* __restrict__ wvp2,
                float* __restrict__ out)
{
    extern __shared__ char SHC[];
    float* SHf = (float*)SHC;
    const int tid = threadIdx.x, s = blockIdx.x;
    const int lane = tid & 63, w = tid >> 6;
    const int q = lane >> 4, l15 = lane & 15, q16 = q * 16;

    for (int i = tid; i < LDSB / 4; i += 256) SHf[i] = 0.f;
    __syncthreads();

    // per-lane column geometry (col = n*16 + l15; 49 live pixels)
    int okc[4], py0[4], px0[4];
    #pragma unroll
    for (int n = 0; n < 4; ++n) {
        int col = n * 16 + l15;
        okc[n] = col < 49;
        int p = okc[n] ? col : 0;
        py0[n] = p / 7; px0[n] = p % 7;
    }

    // ============ PHASE A ============
    const float* xs = x + (size_t)s * 12544;
    for (int e = tid; e < 12544; e += 256) {
        int ch = e / 49, p = e - ch * 49;
        *(_Float16*)(SHC + XPb + p * 528 + ch * 2) = (_Float16)xs[e];
    }
    __syncthreads();                       // XP visible

    const int kofs8[8] = {0, 64, 128, 192, 256, 320, 384, 448};
    const int kofs4[4] = {0, 64, 128, 192};
    const int kofs2[2] = {0, 64};
    const int kofs2h[2] = {128, 192};

    // conv0: M=128 (8 mfrags; wave owns w*2, w*2+1), K=256; XP -> XF(@PL0)
    {
        f32x4 acc2[2][4];
        #pragma unroll
        for (int ii = 0; ii < 2; ++ii)
            #pragma unroll
            for (int n = 0; n < 4; ++n) acc2[ii][n] = (f32x4){0.f, 0.f, 0.f, 0.f};
        conv_mfma_run<8, 2>(SHC, XPb, 528, kofs8, q16, c0hi,
                            8, w * 2, 1, okc, py0, px0, acc2, lane);
        #pragma unroll
        for (int ii = 0; ii < 2; ++ii) {
            f32x4 bb = *(const f32x4*)(b_c0 + (w * 2 + ii) * 16 + q * 4);
            int chB = ((w * 2 + ii) * 16 + q * 4) * 2;
            #pragma unroll
            for (int n = 0; n < 4; ++n) if (okc[n]) {
                int p = n * 16 + l15;
                f16x4 h;
                #pragma unroll
                for (int r = 0; r < 4; ++r)
                    h[r] = (_Float16)fmaxf(acc2[ii][n][r] + bb[r], 0.f);
                *(f16x4*)(SHC + XFb + p * 264 + chB) = h;
            }
        }
    }
    __syncthreads();                       // XF visible; XP dead

    // conv1: M=128, K=128, XF -> XF2(@PL1)
    {
        f32x4 acc2[2][4];
        #pragma unroll
        for (int ii = 0; ii < 2; ++ii)
            #pragma unroll
            for (int n = 0; n < 4; ++n) acc2[ii][n] = (f32x4){0.f, 0.f, 0.f, 0.f};
        conv_mfma_run<4, 2>(SHC, XFb, 264, kofs4, q16, c1hi,
                            8, w * 2, 1, okc, py0, px0, acc2, lane);
        #pragma unroll
        for (int ii = 0; ii < 2; ++ii) {
            f32x4 bb = *(const f32x4*)(b_c1 + (w * 2 + ii) * 16 + q * 4);
            int chB = ((w * 2 + ii) * 16 + q * 4) * 2;
            #pragma unroll
            for (int n = 0; n < 4; ++n) if (okc[n]) {
                int p = n * 16 + l15;
                f16x4 h;
                #pragma unroll
                for (int r = 0; r < 4; ++r)
                    h[r] = (_Float16)fmaxf(acc2[ii][n][r] + bb[r], 0.f);
                *(f16x4*)(SHC + XF2b + p * 264 + chB) = h;
            }
        }
    }
    __syncthreads();                       // XF2 visible; XF dead

    // static gates: st = conv_cs(x_feat) + (cx0b+ch0b) + v_first window.
    // Writes ST (@XP's dead bytes) directly — disjoint from XF2 being read.
    // PL0 (=XF, dead) re-zeroed in the same phase (h0old/h1old = 0 at t=0).
    const int fv = firstv[s];
    {
        f32x4 acc[4][4];
        #pragma unroll
        for (int g = 0; g < 4; ++g)
            #pragma unroll
            for (int n = 0; n < 4; ++n) acc[g][n] = (f32x4){0.f, 0.f, 0.f, 0.f};
        conv_mfma_run<4, 4>(SHC, XF2b, 264, kofs4, q16, cshi,
                            16, w, 4, okc, py0, px0, acc, lane);
        const int fy = fv / 7, fx = fv % 7;
        #pragma unroll
        for (int g = 0; g < 4; ++g) {
            int m0 = g * 64 + w * 16 + q * 4;
            f32x4 b0 = *(const f32x4*)(cx0b + m0);
            f32x4 bh = *(const f32x4*)(ch0b + m0);
            #pragma unroll
            for (int n = 0; n < 4; ++n) {
                acc[g][n] += b0 + bh;
                int dy = fy - py0[n], dx = fx - px0[n];
                if (okc[n] && dy >= -1 && dy <= 1 && dx >= -1 && dx <= 1) {
                    int tap = (dy + 1) * 3 + (dx + 1);
                    acc[g][n] += *(const f32x4*)(wv1 + tap * 256 + m0);
                }
                if (okc[n]) {
                    int p = n * 16 + l15;
                    f16x4 h;
                    #pragma unroll
                    for (int r = 0; r < 4; ++r) h[r] = (_Float16)acc[g][n][r];
                    *(f16x4*)(SHC + STb + p * STSTR + m0 * 2) = h;
                }
            }
        }
    }
    for (int i = tid; i < 12936 / 4; i += 256) SHf[i] = 0.f;   // zero PL0
    __syncthreads();                       // ST + PL0 zeros visible

    // layer-1 biases cached in registers
    f32x4 b1[4];
    #pragma unroll
    for (int g = 0; g < 4; ++g) {
        int m0 = g * 64 + w * 16 + q * 4;
        b1[g] = *(const f32x4*)(cx1b + m0) + *(const f32x4*)(ch1b + m0);
    }

    float c0s[4][4], c1s[4][4];
    #pragma unroll
    for (int n = 0; n < 4; ++n)
        #pragma unroll
        for (int r = 0; r < 4; ++r) { c0s[n][r] = 0.f; c1s[n][r] = 0.f; }

    float* outS = out + (size_t)s * 450;
    int p1 = fv, p2 = 49;                  // preds live in registers

    // accL0 carried across iterations: holds ST + conv_g0(h0old) for step t.
    // t=0: h0old = 0 -> conv term zero -> just ST (conv skipped entirely).
    f32x4 accL0[4][4];
    #pragma unroll
    for (int g = 0; g < 4; ++g) {
        int m0 = g * 64 + w * 16 + q * 4;
        #pragma unroll
        for (int n = 0; n < 4; ++n) {
            int p = okc[n] ? (n * 16 + l15) : 0;
            f16x4 hv = *(const f16x4*)(SHC + STb + p * STSTR + m0 * 2);
            accL0[g][n] = (f32x4){(float)hv[0], (float)hv[1], (float)hv[2], (float)hv[3]};
        }
    }

    // ============ PHASE B: 9 recurrent steps, 3 barriers each ============
    for (int t = 0; t < 9; ++t) {
        const int cur = (t & 1) ? PL1 : PL0;
        const int nxt = (t & 1) ? PL0 : PL1;
        // ---- one-hot injections (commute with the conv already in accL0) ----
        inject_onehot(accL0, wvp1, p1, okc, py0, px0, w, q);
        inject_onehot(accL0, wvp2, p2, okc, py0, px0, w, q);
        {   // L0 LSTM epilogue, write h0new -> nxt h0 (safe: no cur-h0 readers left)
            int chB = (w * 16 + q * 4) * 2;
            #pragma unroll
            for (int n = 0; n < 4; ++n) if (okc[n]) {
                int p = n * 16 + l15;
                f16x4 h;
                #pragma unroll
                for (int r = 0; r < 4; ++r) {
                    float ig = sigmoidf_(accL0[0][n][r]);
                    float fg = sigmoidf_(accL0[1][n][r]);
                    float gg = tanhf_(accL0[2][n][r]);
                    float og = sigmoidf_(accL0[3][n][r]);
                    float cy = fg * c0s[n][r] + ig * gg;
                    c0s[n][r] = cy;
                    h[r] = (_Float16)(og * tanhf_(cy));
                }
                *(f16x4*)(SHC + nxt + p * 264 + chB) = h;
            }
        }
        __syncthreads();                   // [1] h0new visible
        // ---- L1 gates: K = [h0new (nxt) | h1old (cur)] ----
        {
            f32x4 acc[4][4];
            #pragma unroll
            for (int g = 0; g < 4; ++g)
                #pragma unroll
                for (int n = 0; n < 4; ++n) acc[g][n] = b1[g];
            conv_mfma_run<2, 4>(SHC, nxt, 264, kofs2, q16, g1x,
                                16, w, 4, okc, py0, px0, acc, lane);
            conv_mfma_run<2, 4>(SHC, cur, 264, kofs2h, q16, g1h,
                                16, w, 4, okc, py0, px0, acc, lane);
            // L1 epilogue, write h1new -> nxt h1
            int chB = 128 + (w * 16 + q * 4) * 2;
            #pragma unroll
            for (int n = 0; n < 4; ++n) if (okc[n]) {
                int p = n * 16 + l15;
                f16x4 h;
                #pragma unroll
                for (int r = 0; r < 4; ++r) {
                    float ig = sigmoidf_(acc[0][n][r]);
                    float fg = sigmoidf_(acc[1][n][r]);
                    float gg = tanhf_(acc[2][n][r]);
                    float og = sigmoidf_(acc[3][n][r]);
                    float cy = fg * c1s[n][r] + ig * gg;
                    c1s[n][r] = cy;
                    h[r] = (_Float16)(og * tanhf_(cy));
                }
                *(f16x4*)(SHC + nxt + p * 264 + chB) = h;
            }
        }
        __syncthreads();                   // [2] h1new visible
        // ---- region3: FC(t) fused with L0conv(t+1) — independent chains ----
        {
            f32x4 afc[4];
            #pragma unroll
            for (int mi = 0; mi < 4; ++mi) afc[mi] = (f32x4){0.f, 0.f, 0.f, 0.f};
            if (t < 8) {                   // re-init accL0 = ST for step t+1
                #pragma unroll
                for (int g = 0; g < 4; ++g) {
                    int m0 = g * 64 + w * 16 + q * 4;
                    #pragma unroll
                    for (int n = 0; n < 4; ++n) {
                        int p = okc[n] ? (n * 16 + l15) : 0;
                        f16x4 hv = *(const f16x4*)(SHC + STb + p * STSTR + m0 * 2);
                        accL0[g][n] = (f32x4){(float)hv[0], (float)hv[1], (float)hv[2], (float)hv[3]};
                    }
                }
            }
            int kc0 = w * 25;
            int kcN = (w < 3) ? 25 : 23;
            #pragma unroll 1
            for (int it = 0; it < 9; ++it) {
                // fc slice: ~3 k-chunks (M=64, 50 live; col 0 live; K from nxt h1)
                int ks = it * 3, ke = ks + 3; if (ke > kcN) ke = kcN;
                #pragma unroll 1
                for (int kc = ks; kc < ke; ++kc) {
                    int kg = kc0 + kc;
                    int aB = (l15 == 0) ? (nxt + (kg >> 1) * 264 + 128 + (kg & 1) * 64 + q16) : Z512;
                    f16x8 B = *(const f16x8*)(SHC + aB);
                    #pragma unroll
                    for (int mi = 0; mi < 4; ++mi) {
                        int frag = ((kg * 4 + mi) << 9) + lane * 8;
                        f16x8 Ah = *(const f16x8*)(fchi + frag);
                        afc[mi] = __builtin_amdgcn_mfma_f32_16x16x32_f16(Ah, B, afc[mi], 0, 0, 0);
                    }
                }
                if (t < 8) {
                    // L0conv(t+1) tap `it` over h0new (nxt)
                    const int dy = it / 3 - 1, dx = it % 3 - 1;
                    int bb[4];
                    #pragma unroll
                    for (int n = 0; n < 4; ++n) {
                        int py = py0[n] + dy, px = px0[n] + dx;
                        bool ok = okc[n] && ((unsigned)py < 7u) && ((unsigned)px < 7u);
                        bb[n] = ok ? nxt + (py * 7 + px) * 264 : Z512;
                    }
                    #pragma unroll
                    for (int kc = 0; kc < 2; ++kc) {
                        const int kof = kc * 64 + q16;
                        f16x8 B2[4];
                        #pragma unroll
                        for (int n = 0; n < 4; ++n) B2[n] = *(const f16x8*)(SHC + bb[n] + kof);
                        #pragma unroll
                        for (int ii = 0; ii < 4; ++ii) {
                            int frag = (((it * 2 + kc) * 16 + (w + ii * 4)) << 9) + lane * 8;
                            f16x8 Ah = *(const f16x8*)(g0hi + frag);
                            #pragma unroll
                            for (int n = 0; n < 4; ++n)
                                accL0[ii][n] = __builtin_amdgcn_mfma_f32_16x16x32_f16(Ah, B2[n], accL0[ii][n], 0, 0, 0);
                        }
                    }
                }
            }
            if (l15 == 0) {
                #pragma unroll
                for (int mi = 0; mi < 4; ++mi)
                    *(f32x4*)(SHC + FCP + w * 256 + mi * 64 + q16) = afc[mi];
            }
        }
        __syncthreads();                   // [3] fc partials visible
        // redundant per-wave argmax (identical in all waves; pred stays in regs)
        {
            const float* fp = (const float*)(SHC + FCP);
            int c = lane;
            float lg = fp[c] + fp[64 + c] + fp[128 + c] + fp[192 + c];
            float v = -3.4e38f;
            if (c < 50) { lg += fcb[c]; v = lg; }
            if (w == 0 && c < 50) outS[t * 50 + c] = lg;
            int idx = c;
            #pragma unroll
            for (int off = 1; off < 64; off <<= 1) {
                float ov = __shfl_xor(v, off, 64);
                int   oi = __shfl_xor(idx, off, 64);
                if (ov > v || (ov == v && oi < idx)) { v = ov; idx = oi; }
            }
            p2 = p1; p1 = idx;
        }
        // no barrier: FCP rewritten 2 barriers later; cur-h0 overwrite (next
        // epilogue) has no remaining readers.
    }
}

// ================= weight repack kernels =================
// OIHW conv weights -> A fragments [tap][kc][mi][lane][8], single f16
__global__ void repack_frags_k(const float* __restrict__ w, _Float16* __restrict__ o,
                               int ICS, int KMAX, int NKC, int NMF, int total) {
    int i = blockIdx.x * 256 + threadIdx.x;
    if (i >= total) return;
    int j = i & 7, lane = (i >> 3) & 63;
    int rest = i >> 9;
    int mi = rest % NMF; rest /= NMF;
    int kc = rest % NKC; int tap = rest / NKC;
    int m = mi * 16 + (lane & 15);
    int k = kc * 32 + ((lane >> 4) & 3) * 8 + j;
    float v = (k < KMAX) ? w[((size_t)m * ICS + k) * 9 + tap] : 0.f;
    o[i] = (_Float16)v;
}

// fc weights [50][3136] -> frags [kc 98][mi 4][lane][8], k = p*64+ch, single f16
__global__ void repack_fc_k(const float* __restrict__ fcw, _Float16* __restrict__ o) {
    int i = blockIdx.x * 256 + threadIdx.x;
    if (i >= 200704) return;
    int j = i & 7, lane = (i >> 3) & 63;
    int rest = i >> 9;
    int mi = rest & 3, kc = rest >> 2;
    int cls = mi * 16 + (lane & 15);
    int k = kc * 32 + ((lane >> 4) & 3) * 8 + j;
    int ch = k & 63, p = k >> 6;
    float v = (cls < 50) ? fcw[(size_t)cls * 3136 + ch * 49 + p] : 0.f;
    o[i] = (_Float16)v;
}

// one-hot conv tables: wv[tap][m] = cx0w[m, ic, tap]
__global__ void repack_wv_k(const float* __restrict__ cx0w, float* __restrict__ o, int ic) {
    int i = blockIdx.x * 256 + threadIdx.x;
    if (i >= 2304) return;
    int tap = i / 256, m = i % 256;
    o[i] = cx0w[((size_t)m * 131 + ic) * 9 + tap];
}

extern "C" void kernel_launch(void* const* d_in, const int* in_sizes, int n_in,
                              void* d_out, int out_size, void* d_ws, size_t ws_size,
                              hipStream_t stream)
{
    const float* x     = (const float*)d_in[0];
    const int*   fv    = (const int*)  d_in[1];
    const float* c0w   = (const float*)d_in[2];
    const float* c0b   = (const float*)d_in[3];
    const float* c1w   = (const float*)d_in[4];
    const float* c1b   = (const float*)d_in[5];
    const float* cx0w  = (const float*)d_in[6];
    const float* cx0b  = (const float*)d_in[7];
    const float* ch0w  = (const float*)d_in[8];
    const float* ch0b  = (const float*)d_in[9];
    const float* cx1w  = (const float*)d_in[10];
    const float* cx1b  = (const float*)d_in[11];
    const float* ch1w  = (const float*)d_in[12];
    const float* ch1b  = (const float*)d_in[13];
    const float* fcw   = (const float*)d_in[14];
    const float* fcb   = (const float*)d_in[15];
    float* out = (float*)d_out;
    const int n = in_sizes[0] / 12544;

    _Float16* h = (_Float16*)d_ws;
    _Float16* g0hi = h;                  // 147456 (ch0, NKC=2, NMF=16)
    _Float16* g1x  = g0hi + 147456;      // 147456 (cx1, NKC=2)
    _Float16* g1h  = g1x + 147456;       // 147456 (ch1, NKC=2)
    _Float16* c0hi = g1h + 147456;       // 294912
    _Float16* c1hi = c0hi + 294912;      // 147456
    _Float16* cshi = c1hi + 147456;      // 294912
    _Float16* fchi = cshi + 294912;      // 200704
    float*    wv1  = (float*)(fchi + 200704);   // 2304 f32 each
    float*    wvp1 = wv1 + 2304;
    float*    wvp2 = wvp1 + 2304;

    repack_frags_k<<<(147456 + 255) / 256, 256, 0, stream>>>(ch0w, g0hi, 64, 64, 2, 16, 147456);
    repack_frags_k<<<(147456 + 255) / 256, 256, 0, stream>>>(cx1w, g1x, 64, 64, 2, 16, 147456);
    repack_frags_k<<<(147456 + 255) / 256, 256, 0, stream>>>(ch1w, g1h, 64, 64, 2, 16, 147456);
    repack_frags_k<<<(294912 + 255) / 256, 256, 0, stream>>>(c0w, c0hi, 256, 256, 8, 8, 294912);
    repack_frags_k<<<(147456 + 255) / 256, 256, 0, stream>>>(c1w, c1hi, 128, 128, 4, 8, 147456);
    repack_frags_k<<<(294912 + 255) / 256, 256, 0, stream>>>(cx0w, cshi, 131, 128, 4, 16, 294912);
    repack_fc_k   <<<(200704 + 255) / 256, 256, 0, stream>>>(fcw, fchi);
    repack_wv_k   <<<(2304 + 255) / 256, 256, 0, stream>>>(cx0w, wv1, 130);
    repack_wv_k   <<<(2304 + 255) / 256, 256, 0, stream>>>(cx0w, wvp1, 129);
    repack_wv_k   <<<(2304 + 255) / 256, 256, 0, stream>>>(cx0w, wvp2, 128);

    (void)hipFuncSetAttribute((const void*)poly_fused,
                              hipFuncAttributeMaxDynamicSharedMemorySize, LDSB);
    poly_fused<<<n, 256, LDSB, stream>>>(x, fv, c0b, c1b, cx0b, ch0b, cx1b, ch1b, fcb,
                                         c0hi, c1hi, cshi,
                                         g0hi, g1x, g1h, fchi,
                                         wv1, wvp1, wvp2, out);
}